// Round 1
// baseline (16313.541 us; speedup 1.0000x reference)
//
#include <hip/hip_runtime.h>
#include <math.h>

// ---------------------------------------------------------------------------
// LiteEval: gated dual-LSTM.  Round 1: correctness-first all-f32 baseline.
// Strategy:
//   feats  = relu((x @ W_p^T + b_p) * g_p/sqrt(1+eps) + be_p)      [16384,2048]
//   sfeats = relu((xs @ W_s^T + b_s) * g_s/sqrt(1+eps) + be_s)     [16384,512]
//   Gx_l   = [feats|sfeats] @ Wih_l^T + bih_l + bhh_l              [16384,4096]
//   Gx_s   = sfeats @ Wih_s^T + bih_s + bhh_s                      [16384,2048]
//   zs     = sfeats @ W_g[:, :512]^T                               [16384,2]
//   then 64 sequential steps of {small-cell GEMM+update, gate, large-cell
//   GEMM+update}, final logits GEMM.
// Row index convention everywhere: bt = b*64 + t  (matches [B,T,*] layout).
// ---------------------------------------------------------------------------

#define BKK 32

__device__ __forceinline__ float sigf(float x) { return 1.0f / (1.0f + expf(-x)); }

// EPI: 0 = relu((acc+e0[n]) * (e1[n]*c) + e2[n])   (BN+ReLU, c=1/sqrt(1+1e-5))
//      1 = acc + e0[n] + e1[n]                     (two biases)
//      2 = acc + e0[m*e0rs + n]                    (row-add precomputed Gx)
template <int BM, int BN, int TM, int TN, int EPI>
__global__ __launch_bounds__(256) void gemm_nt(
    int M, int N,
    const float* __restrict__ A0, long long as0, const float* __restrict__ B0, long long bs0, int K0,
    const float* __restrict__ A1, long long as1, const float* __restrict__ B1, long long bs1, int K1,
    const float* __restrict__ A2, long long as2, const float* __restrict__ B2, long long bs2, int K2,
    float* __restrict__ C, long long ldc,
    const float* __restrict__ e0, const float* __restrict__ e1, const float* __restrict__ e2,
    long long e0rs)
{
  __shared__ float As[BKK][BM + 4];
  __shared__ float Bs[BKK][BN + 4];
  const int tid = threadIdx.x;
  const int m0 = blockIdx.x * BM;
  const int n0 = blockIdx.y * BN;
  constexpr int C4 = BKK / 4;       // 8 float4 columns per k-tile row
  constexpr int RPP = 256 / C4;     // 32 rows loaded per pass
  constexpr int APASS = BM / RPP;
  constexpr int BPASS = BN / RPP;
  const int lr = tid / C4;          // 0..31
  const int lc = tid % C4;          // 0..7

  float4 pa[APASS], pb[BPASS];
  const int nt = (K0 + K1 + K2) / BKK;

  auto load = [&](int kt) {
    const int kg = kt * BKK;
    const float* ap; long long as_; const float* bp; long long bs_;
    if (kg < K0)            { ap = A0 + kg;               as_ = as0; bp = B0 + kg;               bs_ = bs0; }
    else if (kg < K0 + K1)  { int kl = kg - K0;           ap = A1 + kl; as_ = as1; bp = B1 + kl; bs_ = bs1; }
    else                    { int kl = kg - K0 - K1;      ap = A2 + kl; as_ = as2; bp = B2 + kl; bs_ = bs2; }
#pragma unroll
    for (int p = 0; p < APASS; p++) {
      int r = lr + p * RPP;
      pa[p] = *(const float4*)(ap + (long long)(m0 + r) * as_ + lc * 4);
    }
#pragma unroll
    for (int p = 0; p < BPASS; p++) {
      int r = lr + p * RPP;
      pb[p] = *(const float4*)(bp + (long long)(n0 + r) * bs_ + lc * 4);
    }
  };

  const int tx = tid % (BN / TN);
  const int ty = tid / (BN / TN);
  float acc[TM][TN];
#pragma unroll
  for (int i = 0; i < TM; i++)
#pragma unroll
    for (int j = 0; j < TN; j++) acc[i][j] = 0.0f;

  load(0);
  for (int kt = 0; kt < nt; ++kt) {
    __syncthreads();
    // stage regs -> LDS (transposed: [k][m], [k][n])
#pragma unroll
    for (int p = 0; p < APASS; p++) {
      int r = lr + p * RPP;
      As[lc * 4 + 0][r] = pa[p].x; As[lc * 4 + 1][r] = pa[p].y;
      As[lc * 4 + 2][r] = pa[p].z; As[lc * 4 + 3][r] = pa[p].w;
    }
#pragma unroll
    for (int p = 0; p < BPASS; p++) {
      int r = lr + p * RPP;
      Bs[lc * 4 + 0][r] = pb[p].x; Bs[lc * 4 + 1][r] = pb[p].y;
      Bs[lc * 4 + 2][r] = pb[p].z; Bs[lc * 4 + 3][r] = pb[p].w;
    }
    __syncthreads();
    if (kt + 1 < nt) load(kt + 1);  // prefetch next tile into regs over compute
#pragma unroll
    for (int k = 0; k < BKK; k++) {
      float a[TM], b[TN];
#pragma unroll
      for (int i = 0; i < TM; i++) a[i] = As[k][ty * TM + i];
#pragma unroll
      for (int j = 0; j < TN; j++) b[j] = Bs[k][tx * TN + j];
#pragma unroll
      for (int i = 0; i < TM; i++)
#pragma unroll
        for (int j = 0; j < TN; j++) acc[i][j] += a[i] * b[j];
    }
  }

  // epilogue (TN must be 4: one float4 store per row)
#pragma unroll
  for (int i = 0; i < TM; i++) {
    const int m = m0 + ty * TM + i;
    const int n = n0 + tx * TN;
    float v[TN];
#pragma unroll
    for (int j = 0; j < TN; j++) {
      float a = acc[i][j];
      if (EPI == 0) {
        float s = e1[n + j] * 0.999995f;  // gamma / sqrt(1 + 1e-5)
        a = (a + e0[n + j]) * s + e2[n + j];
        a = fmaxf(a, 0.0f);
      } else if (EPI == 1) {
        a = a + e0[n + j] + e1[n + j];
      } else {
        a = a + e0[(long long)m * e0rs + n + j];
      }
      v[j] = a;
    }
    float4 o; o.x = v[0]; o.y = v[1]; o.z = v[2]; o.w = v[3];
    *(float4*)(C + (long long)m * ldc + n) = o;
  }
}

// zs[bt, g] = sfeats[bt, :512] . W_g[g, :512]   (one wave per row)
__global__ __launch_bounds__(256) void zs_k(const float* __restrict__ sf,
                                            const float* __restrict__ Wg,
                                            float* __restrict__ zs)
{
  const int wave = threadIdx.x >> 6, lane = threadIdx.x & 63;
  const int row = blockIdx.x * 4 + wave;
  const float* s = sf + (long long)row * 512 + lane * 8;
  const float* w0 = Wg + lane * 8;
  const float* w1 = Wg + 2560 + lane * 8;
  float4 sa = *(const float4*)s, sb = *(const float4*)(s + 4);
  float4 a0 = *(const float4*)w0, b0 = *(const float4*)(w0 + 4);
  float4 a1 = *(const float4*)w1, b1 = *(const float4*)(w1 + 4);
  float z0 = sa.x * a0.x + sa.y * a0.y + sa.z * a0.z + sa.w * a0.w
           + sb.x * b0.x + sb.y * b0.y + sb.z * b0.z + sb.w * b0.w;
  float z1 = sa.x * a1.x + sa.y * a1.y + sa.z * a1.z + sa.w * a1.w
           + sb.x * b1.x + sb.y * b1.y + sb.z * b1.z + sb.w * b1.w;
#pragma unroll
  for (int off = 32; off > 0; off >>= 1) {
    z0 += __shfl_down(z0, off);
    z1 += __shfl_down(z1, off);
  }
  if (lane == 0) { zs[row * 2] = z0; zs[row * 2 + 1] = z1; }
}

// gate: z = zs[bt] + h_l.Wg[:,512:1536] + c_l.Wg[:,1536:2560] + b_g -> one-hot
__global__ __launch_bounds__(256) void gate_k(const float* __restrict__ hl,
                                              const float* __restrict__ cl,
                                              const float* __restrict__ zs,
                                              const float* __restrict__ Wg,
                                              const float* __restrict__ bg,
                                              float* __restrict__ rout, int t)
{
  const int b = blockIdx.x, tid = threadIdx.x;
  float4 h4 = *(const float4*)(hl + (long long)b * 1024 + tid * 4);
  float4 c4 = *(const float4*)(cl + (long long)b * 1024 + tid * 4);
  float4 w0h = *(const float4*)(Wg + 512 + tid * 4);
  float4 w0c = *(const float4*)(Wg + 1536 + tid * 4);
  float4 w1h = *(const float4*)(Wg + 2560 + 512 + tid * 4);
  float4 w1c = *(const float4*)(Wg + 2560 + 1536 + tid * 4);
  float z0 = h4.x * w0h.x + h4.y * w0h.y + h4.z * w0h.z + h4.w * w0h.w
           + c4.x * w0c.x + c4.y * w0c.y + c4.z * w0c.z + c4.w * w0c.w;
  float z1 = h4.x * w1h.x + h4.y * w1h.y + h4.z * w1h.z + h4.w * w1h.w
           + c4.x * w1c.x + c4.y * w1c.y + c4.z * w1c.z + c4.w * w1c.w;
  __shared__ float s0[256], s1[256];
  s0[tid] = z0; s1[tid] = z1;
  __syncthreads();
  for (int s = 128; s > 0; s >>= 1) {
    if (tid < s) { s0[tid] += s0[tid + s]; s1[tid] += s1[tid + s]; }
    __syncthreads();
  }
  if (tid == 0) {
    float zz0 = s0[0] + zs[(b * 64 + t) * 2 + 0] + bg[0];
    float zz1 = s1[0] + zs[(b * 64 + t) * 2 + 1] + bg[1];
    int idx = (zz1 > zz0) ? 1 : 0;   // jnp.argmax: ties -> index 0
    rout[b * 2 + 0] = (idx == 0) ? 1.0f : 0.0f;
    rout[b * 2 + 1] = (idx == 1) ? 1.0f : 0.0f;
  }
}

// small cell elementwise update: gates [256,2048] (i,f,g,o), S=512
__global__ __launch_bounds__(256) void upd_small_k(const float* __restrict__ g,
                                                   const float* __restrict__ c_old,
                                                   float* __restrict__ h_new,
                                                   float* __restrict__ c_new)
{
  const int idx = blockIdx.x * 256 + threadIdx.x;   // 256*512
  const int b = idx >> 9, n = idx & 511;
  const float* gb = g + (long long)b * 2048;
  float gi = gb[n], gf = gb[512 + n], gg = gb[1024 + n], go = gb[1536 + n];
  float c2 = sigf(gf) * c_old[idx] + sigf(gi) * tanhf(gg);
  float h2 = sigf(go) * tanhf(c2);
  c_new[idx] = c2; h_new[idx] = h2;
}

// large cell update + straight-through gating. gates [256,4096], L=1024, S=512
__global__ __launch_bounds__(256) void upd_large_k(const float* __restrict__ g,
                                                   const float* __restrict__ h_old,
                                                   const float* __restrict__ c_old,
                                                   const float* __restrict__ hs_new,
                                                   const float* __restrict__ cs_new,
                                                   const float* __restrict__ r,
                                                   float* __restrict__ h_new,
                                                   float* __restrict__ c_new)
{
  const int idx = blockIdx.x * 256 + threadIdx.x;   // 256*1024
  const int b = idx >> 10, n = idx & 1023;
  const float* gb = g + (long long)b * 4096;
  float gi = gb[n], gf = gb[1024 + n], gg = gb[2048 + n], go = gb[3072 + n];
  float cln = sigf(gf) * c_old[idx] + sigf(gi) * tanhf(gg);
  float hln = sigf(go) * tanhf(cln);
  float ph = (n < 512) ? hs_new[b * 512 + n] : h_old[idx];
  float pc = (n < 512) ? cs_new[b * 512 + n] : c_old[idx];
  float r0 = r[b * 2], r1 = r[b * 2 + 1];
  h_new[idx] = r0 * hln + r1 * ph;
  c_new[idx] = r0 * cln + r1 * pc;
}

// logits = h_l @ W_c^T + b_c   (one block per batch row)
__global__ __launch_bounds__(256) void logits_k(const float* __restrict__ hl,
                                                const float* __restrict__ Wc,
                                                const float* __restrict__ bc,
                                                float* __restrict__ out)
{
  __shared__ float hs[1024];
  const int b = blockIdx.x, tid = threadIdx.x;
  *(float4*)(hs + tid * 4) = *(const float4*)(hl + (long long)b * 1024 + tid * 4);
  __syncthreads();
  if (tid < 239) {
    const float* w = Wc + (long long)tid * 1024;
    float s = 0.0f;
    for (int k = 0; k < 1024; k += 4) {
      float4 wv = *(const float4*)(w + k);
      s += hs[k] * wv.x + hs[k + 1] * wv.y + hs[k + 2] * wv.z + hs[k + 3] * wv.w;
    }
    out[(long long)b * 239 + tid] = s + bc[tid];
  }
}

extern "C" void kernel_launch(void* const* d_in, const int* in_sizes, int n_in,
                              void* d_out, int out_size, void* d_ws, size_t ws_size,
                              hipStream_t stream)
{
  const float* x     = (const float*)d_in[0];
  const float* xs    = (const float*)d_in[1];
  const float* W_p   = (const float*)d_in[2];
  const float* b_p   = (const float*)d_in[3];
  const float* g_p   = (const float*)d_in[4];
  const float* be_p  = (const float*)d_in[5];
  const float* W_s   = (const float*)d_in[6];
  const float* b_s   = (const float*)d_in[7];
  const float* g_s   = (const float*)d_in[8];
  const float* be_s  = (const float*)d_in[9];
  const float* Wih_l = (const float*)d_in[10];
  const float* Whh_l = (const float*)d_in[11];
  const float* bih_l = (const float*)d_in[12];
  const float* bhh_l = (const float*)d_in[13];
  const float* Wih_s = (const float*)d_in[14];
  const float* Whh_s = (const float*)d_in[15];
  const float* bih_s = (const float*)d_in[16];
  const float* bhh_s = (const float*)d_in[17];
  const float* W_g   = (const float*)d_in[18];
  const float* b_g   = (const float*)d_in[19];
  const float* W_c   = (const float*)d_in[20];
  const float* b_c   = (const float*)d_in[21];
  float* out = (float*)d_out;

  const int BT = 16384;   // 256 * 64

  float* ws = (float*)d_ws;
  size_t off = 0;
  auto alloc = [&](size_t n) { float* p = ws + off; off += n; return p; };
  float* feats   = alloc((size_t)BT * 2048);
  float* sfeats  = alloc((size_t)BT * 512);
  float* zs      = alloc((size_t)BT * 2);
  float* gates_l = alloc((size_t)256 * 4096);
  float* gates_s = alloc((size_t)256 * 2048);
  float* hl[2] = { alloc(256 * 1024), alloc(256 * 1024) };
  float* cl[2] = { alloc(256 * 1024), alloc(256 * 1024) };
  float* hs[2] = { alloc(256 * 512),  alloc(256 * 512) };
  float* cs[2] = { alloc(256 * 512),  alloc(256 * 512) };
  const size_t base_floats = off;
  float* Gx_l = nullptr; float* Gx_s = nullptr;
  const size_t full_floats = base_floats + (size_t)BT * 4096 + (size_t)BT * 2048;
  const bool precomp = ws_size >= full_floats * sizeof(float);
  if (precomp) {
    Gx_l = alloc((size_t)BT * 4096);
    Gx_s = alloc((size_t)BT * 2048);
  }

  // zero initial states
  hipMemsetAsync(hl[0], 0, 256 * 1024 * sizeof(float), stream);
  hipMemsetAsync(cl[0], 0, 256 * 1024 * sizeof(float), stream);
  hipMemsetAsync(hs[0], 0, 256 * 512 * sizeof(float), stream);
  hipMemsetAsync(cs[0], 0, 256 * 512 * sizeof(float), stream);

  // feats = BN_ReLU(x @ W_p^T + b_p)
  gemm_nt<128, 64, 8, 4, 0><<<dim3(BT / 128, 2048 / 64), 256, 0, stream>>>(
      BT, 2048,
      x, 2048, W_p, 2048, 2048,
      nullptr, 0, nullptr, 0, 0,
      nullptr, 0, nullptr, 0, 0,
      feats, 2048, b_p, g_p, be_p, 0);
  // sfeats = BN_ReLU(xs @ W_s^T + b_s)
  gemm_nt<128, 64, 8, 4, 0><<<dim3(BT / 128, 512 / 64), 256, 0, stream>>>(
      BT, 512,
      xs, 1280, W_s, 1280, 1280,
      nullptr, 0, nullptr, 0, 0,
      nullptr, 0, nullptr, 0, 0,
      sfeats, 512, b_s, g_s, be_s, 0);
  // zs
  zs_k<<<BT / 4, 256, 0, stream>>>(sfeats, W_g, zs);

  if (precomp) {
    // Gx_l = [feats|sfeats] @ Wih_l^T + bih_l + bhh_l
    gemm_nt<128, 64, 8, 4, 1><<<dim3(BT / 128, 4096 / 64), 256, 0, stream>>>(
        BT, 4096,
        feats, 2048, Wih_l, 2560, 2048,
        sfeats, 512, Wih_l + 2048, 2560, 512,
        nullptr, 0, nullptr, 0, 0,
        Gx_l, 4096, bih_l, bhh_l, nullptr, 0);
    // Gx_s = sfeats @ Wih_s^T + bih_s + bhh_s
    gemm_nt<128, 64, 8, 4, 1><<<dim3(BT / 128, 2048 / 64), 256, 0, stream>>>(
        BT, 2048,
        sfeats, 512, Wih_s, 512, 512,
        nullptr, 0, nullptr, 0, 0,
        nullptr, 0, nullptr, 0, 0,
        Gx_s, 2048, bih_s, bhh_s, nullptr, 0);
  }

  for (int t = 0; t < 64; ++t) {
    const int o = t & 1, nw = o ^ 1;
    // small cell gates
    if (precomp) {
      gemm_nt<64, 64, 4, 4, 2><<<dim3(4, 2048 / 64), 256, 0, stream>>>(
          256, 2048,
          hs[o], 512, Whh_s, 512, 512,
          nullptr, 0, nullptr, 0, 0,
          nullptr, 0, nullptr, 0, 0,
          gates_s, 2048, Gx_s + (long long)t * 2048, nullptr, nullptr, 64LL * 2048);
    } else {
      gemm_nt<64, 64, 4, 4, 1><<<dim3(4, 2048 / 64), 256, 0, stream>>>(
          256, 2048,
          sfeats + (long long)t * 512, 64LL * 512, Wih_s, 512, 512,
          hs[o], 512, Whh_s, 512, 512,
          nullptr, 0, nullptr, 0, 0,
          gates_s, 2048, bih_s, bhh_s, nullptr, 0);
    }
    upd_small_k<<<512, 256, 0, stream>>>(gates_s, cs[o], hs[nw], cs[nw]);
    // gate on OLD large state
    gate_k<<<256, 256, 0, stream>>>(hl[o], cl[o], zs, W_g, b_g,
                                    out + 61184 + (long long)t * 512, t);
    // large cell gates
    if (precomp) {
      gemm_nt<64, 64, 4, 4, 2><<<dim3(4, 4096 / 64), 256, 0, stream>>>(
          256, 4096,
          hl[o], 1024, Whh_l, 1024, 1024,
          nullptr, 0, nullptr, 0, 0,
          nullptr, 0, nullptr, 0, 0,
          gates_l, 4096, Gx_l + (long long)t * 4096, nullptr, nullptr, 64LL * 4096);
    } else {
      gemm_nt<64, 64, 4, 4, 1><<<dim3(4, 4096 / 64), 256, 0, stream>>>(
          256, 4096,
          feats + (long long)t * 2048, 64LL * 2048, Wih_l, 2560, 2048,
          sfeats + (long long)t * 512, 64LL * 512, Wih_l + 2048, 2560, 512,
          hl[o], 1024, Whh_l, 1024, 1024,
          gates_l, 4096, bih_l, bhh_l, nullptr, 0);
    }
    upd_large_k<<<1024, 256, 0, stream>>>(gates_l, hl[o], cl[o], hs[nw], cs[nw],
                                          out + 61184 + (long long)t * 512,
                                          hl[nw], cl[nw]);
  }

  // logits from final h_l (after t=63, new state is in buffer 0)
  logits_k<<<256, 256, 0, stream>>>(hl[0], W_c, b_c, out);
}

// Round 2
// 16310.716 us; speedup vs baseline: 1.0002x; 1.0002x over previous
//
#include <hip/hip_runtime.h>
#include <math.h>

// ---------------------------------------------------------------------------
// LiteEval gated dual-LSTM.  Round 2:
//   * Big time-parallel GEMMs -> f16 hi/lo split MFMA (3 MFMA per k-frag,
//     f32 accumulate; error ~2^-22 rel, safe for the 16384 argmax decisions).
//     m97-style structure: 128x128 tile, BK=32, 4 waves, global_load_lds(16B).
//   * Sequential part: 2 launches/step (combined dual-cell GEMM with float4
//     LDS reads; fused gate+small+large update), f32 for margin safety.
//   * Fallback to Round-1 all-f32 path if workspace < 754 MB.
// ---------------------------------------------------------------------------

typedef _Float16 f16;
typedef _Float16 f16x8 __attribute__((ext_vector_type(8)));
typedef _Float16 f16x4 __attribute__((ext_vector_type(4)));
typedef float f32x4 __attribute__((ext_vector_type(4)));

#define BKK 32

__device__ __forceinline__ float sigf(float x) { return 1.0f / (1.0f + expf(-x)); }

__device__ __forceinline__ void gload16(const void* g, void* l) {
  __builtin_amdgcn_global_load_lds((const __attribute__((address_space(1))) void*)g,
                                   (__attribute__((address_space(3))) void*)l, 16, 0, 0);
}

// ---------------------------------------------------------------------------
// split f32 -> f16 hi + f16 lo (4 elems/thread)
__global__ __launch_bounds__(256) void split_k4(const float4* __restrict__ in,
                                                f16x4* __restrict__ hi,
                                                f16x4* __restrict__ lo, int n4)
{
  int i = blockIdx.x * 256 + threadIdx.x;
  if (i >= n4) return;
  float4 v = in[i];
  f16x4 h, l;
  h[0] = (f16)v.x; l[0] = (f16)(v.x - (float)h[0]);
  h[1] = (f16)v.y; l[1] = (f16)(v.y - (float)h[1]);
  h[2] = (f16)v.z; l[2] = (f16)(v.z - (float)h[2]);
  h[3] = (f16)v.w; l[3] = (f16)(v.w - (float)h[3]);
  hi[i] = h; lo[i] = l;
}

// ---------------------------------------------------------------------------
// f16-split MFMA GEMM:  C[m][n] = sum_k A[m][k]*B[n][k]  (+ epilogue)
// A in two K-segments (hi/lo pairs), B one segment (hi/lo).
// 128x128 tile, BK=32, 256 thr = 4 waves, wave w stages tile w (Ah/Al/Bh/Bl).
// EPI 0: v = relu((acc+e0[n])*(e1[n]*c) + e2[n]);  EPI 1: v = acc+e0[n]+e1[n]
// Outputs: optional f32 C, optional f16 split (Ch,Cl).
template <int EPI>
__global__ __launch_bounds__(256) void gemm_mfma(
    const f16* __restrict__ Ah0, const f16* __restrict__ Al0, int lda0, int K0,
    const f16* __restrict__ Ah1, const f16* __restrict__ Al1, int lda1, int K1,
    const f16* __restrict__ Bh, const f16* __restrict__ Bl, int ldb,
    float* __restrict__ C, f16* __restrict__ Ch, f16* __restrict__ Cl, int ldc,
    const float* __restrict__ e0, const float* __restrict__ e1,
    const float* __restrict__ e2)
{
  __shared__ f16 lds[4][128 * 32];
  const int tid = threadIdx.x;
  const int w = tid >> 6, lane = tid & 63;
  const int m0 = blockIdx.x * 128, n0 = blockIdx.y * 128;
  const int wr = w >> 1, wc = w & 1;
  const int srow = lane >> 2;          // staging row-in-group 0..15
  const int scol = (lane & 3) * 8;     // staging k-col 0,8,16,24
  const int fr = lane & 15, fq = lane >> 4;

  f32x4 acc[4][4];
#pragma unroll
  for (int i = 0; i < 4; i++)
#pragma unroll
    for (int j = 0; j < 4; j++) acc[i][j] = (f32x4){0.f, 0.f, 0.f, 0.f};

  const int nt = (K0 + K1) >> 5;
  for (int kt = 0; kt < nt; ++kt) {
    const int kg = kt << 5;
    // ---- stage: wave w loads its 128x32 f16 tile via global_load_lds(16B)
    {
      const f16* src;
      long long stride;
      if (w < 2) {
        const f16* Ah = Ah0; const f16* Al = Al0; int lda = lda0; int kl = kg;
        if (kg >= K0) { Ah = Ah1; Al = Al1; lda = lda1; kl = kg - K0; }
        src = ((w == 0) ? Ah : Al) + (long long)(m0 + srow) * lda + kl + scol;
        stride = lda;
      } else {
        src = ((w == 2) ? Bh : Bl) + (long long)(n0 + srow) * ldb + kg + scol;
        stride = ldb;
      }
      f16* dst = &lds[w][0];
#pragma unroll
      for (int j = 0; j < 8; ++j)
        gload16(src + (long long)j * 16 * stride, dst + j * 512);
    }
    __syncthreads();
    // ---- compute: 4x4 fragments x 3 split-combos = 48 MFMA
    const int aoff = (wr * 64 + fr) * 32 + fq * 8;
    const int boff = (wc * 64 + fr) * 32 + fq * 8;
    f16x8 bhf[4], blf[4];
#pragma unroll
    for (int n = 0; n < 4; ++n) {
      bhf[n] = *(const f16x8*)&lds[2][boff + n * 512];
      blf[n] = *(const f16x8*)&lds[3][boff + n * 512];
    }
#pragma unroll
    for (int m = 0; m < 4; ++m) {
      f16x8 ah = *(const f16x8*)&lds[0][aoff + m * 512];
      f16x8 al = *(const f16x8*)&lds[1][aoff + m * 512];
#pragma unroll
      for (int n = 0; n < 4; ++n) {
        acc[m][n] = __builtin_amdgcn_mfma_f32_16x16x32_f16(ah, bhf[n], acc[m][n], 0, 0, 0);
        acc[m][n] = __builtin_amdgcn_mfma_f32_16x16x32_f16(ah, blf[n], acc[m][n], 0, 0, 0);
        acc[m][n] = __builtin_amdgcn_mfma_f32_16x16x32_f16(al, bhf[n], acc[m][n], 0, 0, 0);
      }
    }
    __syncthreads();
  }

  // ---- epilogue: D lane mapping col = lane&15, row = (lane>>4)*4 + reg
#pragma unroll
  for (int m = 0; m < 4; ++m) {
#pragma unroll
    for (int n = 0; n < 4; ++n) {
      const int col = n0 + wc * 64 + n * 16 + fr;
      float b0v = 0.f, b1v = 0.f, b2v = 0.f;
      if (EPI == 0) { b0v = e0[col]; b1v = e1[col] * 0.99999500003750f; b2v = e2[col]; }
      else          { b0v = e0[col] + e1[col]; }
#pragma unroll
      for (int r = 0; r < 4; ++r) {
        const int row = m0 + wr * 64 + m * 16 + fq * 4 + r;
        float v = acc[m][n][r];
        if (EPI == 0) v = fmaxf((v + b0v) * b1v + b2v, 0.0f);
        else          v = v + b0v;
        const long long idx = (long long)row * ldc + col;
        if (C) C[idx] = v;
        if (Ch) { f16 h = (f16)v; Ch[idx] = h; Cl[idx] = (f16)(v - (float)h); }
      }
    }
  }
}

// ---------------------------------------------------------------------------
// combined per-step recurrent GEMM (f32):
//   blockIdx.y <  64: gates_l[b][n] = hl.Whh_l[n] + Gl[b*64*4096 + n]
//   blockIdx.y >= 64: gates_s[b][n] = hs.Whh_s[n] + Gs[b*64*2048 + n]
__global__ __launch_bounds__(256) void step_gemm(
    const float* __restrict__ hl, const float* __restrict__ hs,
    const float* __restrict__ Whl, const float* __restrict__ Whs,
    const float* __restrict__ Gl, const float* __restrict__ Gs,
    float* __restrict__ gl, float* __restrict__ gs)
{
  __shared__ float As[32][68];
  __shared__ float Bs[32][68];
  const int tid = threadIdx.x;
  const bool big = blockIdx.y < 64;
  const float* A = big ? hl : hs;
  const float* B = big ? Whl : Whs;
  const float* G = big ? Gl : Gs;
  float* Cc      = big ? gl : gs;
  const int K    = big ? 1024 : 512;
  const int ldc  = big ? 4096 : 2048;
  const long long gld = big ? (64LL * 4096) : (64LL * 2048);
  const int n0 = (big ? blockIdx.y : (blockIdx.y - 64)) * 64;
  const int m0 = blockIdx.x * 64;

  const int lr = tid >> 3, lc = tid & 7;
  const int tx = tid & 15, ty = tid >> 4;

  float4 pa[2], pb[2];
  const int nt = K >> 5;
  auto load = [&](int kt) {
    const int k = kt * 32 + lc * 4;
#pragma unroll
    for (int p = 0; p < 2; ++p) {
      pa[p] = *(const float4*)(A + (long long)(m0 + lr + p * 32) * K + k);
      pb[p] = *(const float4*)(B + (long long)(n0 + lr + p * 32) * K + k);
    }
  };

  float acc[4][4];
#pragma unroll
  for (int i = 0; i < 4; i++)
#pragma unroll
    for (int j = 0; j < 4; j++) acc[i][j] = 0.0f;

  load(0);
  for (int kt = 0; kt < nt; ++kt) {
    __syncthreads();
#pragma unroll
    for (int p = 0; p < 2; ++p) {
      As[lc * 4 + 0][lr + p * 32] = pa[p].x; As[lc * 4 + 1][lr + p * 32] = pa[p].y;
      As[lc * 4 + 2][lr + p * 32] = pa[p].z; As[lc * 4 + 3][lr + p * 32] = pa[p].w;
      Bs[lc * 4 + 0][lr + p * 32] = pb[p].x; Bs[lc * 4 + 1][lr + p * 32] = pb[p].y;
      Bs[lc * 4 + 2][lr + p * 32] = pb[p].z; Bs[lc * 4 + 3][lr + p * 32] = pb[p].w;
    }
    __syncthreads();
    if (kt + 1 < nt) load(kt + 1);
#pragma unroll
    for (int k = 0; k < 32; ++k) {
      float4 a4 = *(const float4*)&As[k][ty * 4];
      float4 b4 = *(const float4*)&Bs[k][tx * 4];
      acc[0][0] += a4.x * b4.x; acc[0][1] += a4.x * b4.y; acc[0][2] += a4.x * b4.z; acc[0][3] += a4.x * b4.w;
      acc[1][0] += a4.y * b4.x; acc[1][1] += a4.y * b4.y; acc[1][2] += a4.y * b4.z; acc[1][3] += a4.y * b4.w;
      acc[2][0] += a4.z * b4.x; acc[2][1] += a4.z * b4.y; acc[2][2] += a4.z * b4.z; acc[2][3] += a4.z * b4.w;
      acc[3][0] += a4.w * b4.x; acc[3][1] += a4.w * b4.y; acc[3][2] += a4.w * b4.z; acc[3][3] += a4.w * b4.w;
    }
  }

#pragma unroll
  for (int i = 0; i < 4; ++i) {
    const int m = m0 + ty * 4 + i;
    const int n = n0 + tx * 4;
    float4 g4 = *(const float4*)(G + (long long)m * gld + n);
    float4 o;
    o.x = acc[i][0] + g4.x; o.y = acc[i][1] + g4.y;
    o.z = acc[i][2] + g4.z; o.w = acc[i][3] + g4.w;
    *(float4*)(Cc + (long long)m * ldc + n) = o;
  }
}

// ---------------------------------------------------------------------------
// fused per-step update: gate argmax + small-cell update + large-cell blend.
// one block per batch row.
__global__ __launch_bounds__(256) void step_upd(
    const float* __restrict__ gl, const float* __restrict__ gs,
    const float* __restrict__ hl_o, const float* __restrict__ cl_o,
    const float* __restrict__ cs_o,
    float* __restrict__ hl_n, float* __restrict__ cl_n,
    float* __restrict__ hs_n, float* __restrict__ cs_n,
    const float* __restrict__ zs, const float* __restrict__ Wg,
    const float* __restrict__ bg, float* __restrict__ rout, int t)
{
  const int b = blockIdx.x, tid = threadIdx.x;
  __shared__ float red0[256], red1[256];
  __shared__ float shs[512], scs[512];
  __shared__ float rsh[2];

  // gate partials over OLD large state
  float4 h4 = *(const float4*)(hl_o + (long long)b * 1024 + tid * 4);
  float4 c4 = *(const float4*)(cl_o + (long long)b * 1024 + tid * 4);
  float4 w0h = *(const float4*)(Wg + 512 + tid * 4);
  float4 w0c = *(const float4*)(Wg + 1536 + tid * 4);
  float4 w1h = *(const float4*)(Wg + 2560 + 512 + tid * 4);
  float4 w1c = *(const float4*)(Wg + 2560 + 1536 + tid * 4);
  red0[tid] = h4.x * w0h.x + h4.y * w0h.y + h4.z * w0h.z + h4.w * w0h.w
            + c4.x * w0c.x + c4.y * w0c.y + c4.z * w0c.z + c4.w * w0c.w;
  red1[tid] = h4.x * w1h.x + h4.y * w1h.y + h4.z * w1h.z + h4.w * w1h.w
            + c4.x * w1c.x + c4.y * w1c.y + c4.z * w1c.z + c4.w * w1c.w;

  // small-cell update (2 elems/thread), stash new state in LDS
  {
    const float* gb = gs + (long long)b * 2048;
#pragma unroll
    for (int e = 0; e < 2; ++e) {
      const int n = tid * 2 + e;
      float gi = gb[n], gf = gb[512 + n], gg = gb[1024 + n], go = gb[1536 + n];
      float c2 = sigf(gf) * cs_o[b * 512 + n] + sigf(gi) * tanhf(gg);
      float h2 = sigf(go) * tanhf(c2);
      shs[n] = h2; scs[n] = c2;
      hs_n[b * 512 + n] = h2; cs_n[b * 512 + n] = c2;
    }
  }
  __syncthreads();
  for (int s = 128; s > 0; s >>= 1) {
    if (tid < s) { red0[tid] += red0[tid + s]; red1[tid] += red1[tid + s]; }
    __syncthreads();
  }
  if (tid == 0) {
    float z0 = red0[0] + zs[(b * 64 + t) * 2 + 0] + bg[0];
    float z1 = red1[0] + zs[(b * 64 + t) * 2 + 1] + bg[1];
    int hard = (z1 > z0) ? 1 : 0;   // jnp.argmax ties -> 0
    rsh[0] = hard ? 0.0f : 1.0f; rsh[1] = hard ? 1.0f : 0.0f;
    rout[b * 2 + 0] = rsh[0]; rout[b * 2 + 1] = rsh[1];
  }
  __syncthreads();
  const float r0 = rsh[0], r1 = rsh[1];

  // large-cell update + straight-through blend (4 elems/thread)
  {
    const float* glb = gl + (long long)b * 4096;
    const int n = tid * 4;
    float4 gi4 = *(const float4*)(glb + n);
    float4 gf4 = *(const float4*)(glb + 1024 + n);
    float4 gg4 = *(const float4*)(glb + 2048 + n);
    float4 go4 = *(const float4*)(glb + 3072 + n);
    float4 co4 = *(const float4*)(cl_o + (long long)b * 1024 + n);
    float4 ho4 = *(const float4*)(hl_o + (long long)b * 1024 + n);
    float gi[4] = {gi4.x, gi4.y, gi4.z, gi4.w};
    float gf[4] = {gf4.x, gf4.y, gf4.z, gf4.w};
    float gg[4] = {gg4.x, gg4.y, gg4.z, gg4.w};
    float go[4] = {go4.x, go4.y, go4.z, go4.w};
    float co[4] = {co4.x, co4.y, co4.z, co4.w};
    float ho[4] = {ho4.x, ho4.y, ho4.z, ho4.w};
    float hv[4], cv[4];
#pragma unroll
    for (int e = 0; e < 4; ++e) {
      float cln = sigf(gf[e]) * co[e] + sigf(gi[e]) * tanhf(gg[e]);
      float hln = sigf(go[e]) * tanhf(cln);
      float ph = (n + e < 512) ? shs[n + e] : ho[e];
      float pc = (n + e < 512) ? scs[n + e] : co[e];
      hv[e] = r0 * hln + r1 * ph;
      cv[e] = r0 * cln + r1 * pc;
    }
    float4 hw = {hv[0], hv[1], hv[2], hv[3]};
    float4 cw = {cv[0], cv[1], cv[2], cv[3]};
    *(float4*)(hl_n + (long long)b * 1024 + n) = hw;
    *(float4*)(cl_n + (long long)b * 1024 + n) = cw;
  }
}

// ---------------------------------------------------------------------------
// zs[bt,g] = sfeats[bt,:512] . W_g[g,:512]
__global__ __launch_bounds__(256) void zs_k(const float* __restrict__ sf,
                                            const float* __restrict__ Wg,
                                            float* __restrict__ zs)
{
  const int wave = threadIdx.x >> 6, lane = threadIdx.x & 63;
  const int row = blockIdx.x * 4 + wave;
  const float* s = sf + (long long)row * 512 + lane * 8;
  const float* w0 = Wg + lane * 8;
  const float* w1 = Wg + 2560 + lane * 8;
  float4 sa = *(const float4*)s, sb = *(const float4*)(s + 4);
  float4 a0 = *(const float4*)w0, b0 = *(const float4*)(w0 + 4);
  float4 a1 = *(const float4*)w1, b1 = *(const float4*)(w1 + 4);
  float z0 = sa.x * a0.x + sa.y * a0.y + sa.z * a0.z + sa.w * a0.w
           + sb.x * b0.x + sb.y * b0.y + sb.z * b0.z + sb.w * b0.w;
  float z1 = sa.x * a1.x + sa.y * a1.y + sa.z * a1.z + sa.w * a1.w
           + sb.x * b1.x + sb.y * b1.y + sb.z * b1.z + sb.w * b1.w;
#pragma unroll
  for (int off = 32; off > 0; off >>= 1) {
    z0 += __shfl_down(z0, off);
    z1 += __shfl_down(z1, off);
  }
  if (lane == 0) { zs[row * 2] = z0; zs[row * 2 + 1] = z1; }
}

// logits = h_l @ W_c^T + b_c
__global__ __launch_bounds__(256) void logits_k(const float* __restrict__ hl,
                                                const float* __restrict__ Wc,
                                                const float* __restrict__ bc,
                                                float* __restrict__ out)
{
  __shared__ float hsd[1024];
  const int b = blockIdx.x, tid = threadIdx.x;
  *(float4*)(hsd + tid * 4) = *(const float4*)(hl + (long long)b * 1024 + tid * 4);
  __syncthreads();
  if (tid < 239) {
    const float* w = Wc + (long long)tid * 1024;
    float s = 0.0f;
    for (int k = 0; k < 1024; k += 4) {
      float4 wv = *(const float4*)(w + k);
      s += hsd[k] * wv.x + hsd[k + 1] * wv.y + hsd[k + 2] * wv.z + hsd[k + 3] * wv.w;
    }
    out[(long long)b * 239 + tid] = s + bc[tid];
  }
}

// ===========================================================================
// Round-1 fallback kernels (all-f32) — retained for small-workspace safety.
template <int BM, int BN, int TM, int TN, int EPI>
__global__ __launch_bounds__(256) void gemm_nt(
    int M, int N,
    const float* __restrict__ A0, long long as0, const float* __restrict__ B0, long long bs0, int K0,
    const float* __restrict__ A1, long long as1, const float* __restrict__ B1, long long bs1, int K1,
    const float* __restrict__ A2, long long as2, const float* __restrict__ B2, long long bs2, int K2,
    float* __restrict__ C, long long ldc,
    const float* __restrict__ e0, const float* __restrict__ e1, const float* __restrict__ e2,
    long long e0rs)
{
  __shared__ float As[BKK][BM + 4];
  __shared__ float Bs[BKK][BN + 4];
  const int tid = threadIdx.x;
  const int m0 = blockIdx.x * BM;
  const int n0 = blockIdx.y * BN;
  constexpr int C4 = BKK / 4;
  constexpr int RPP = 256 / C4;
  constexpr int APASS = BM / RPP;
  constexpr int BPASS = BN / RPP;
  const int lr = tid / C4;
  const int lc = tid % C4;

  float4 pa[APASS], pb[BPASS];
  const int nt = (K0 + K1 + K2) / BKK;

  auto load = [&](int kt) {
    const int kg = kt * BKK;
    const float* ap; long long as_; const float* bp; long long bs_;
    if (kg < K0)           { ap = A0 + kg;          as_ = as0; bp = B0 + kg;          bs_ = bs0; }
    else if (kg < K0 + K1) { int kl = kg - K0;      ap = A1 + kl; as_ = as1; bp = B1 + kl; bs_ = bs1; }
    else                   { int kl = kg - K0 - K1; ap = A2 + kl; as_ = as2; bp = B2 + kl; bs_ = bs2; }
#pragma unroll
    for (int p = 0; p < APASS; p++) {
      int r = lr + p * RPP;
      pa[p] = *(const float4*)(ap + (long long)(m0 + r) * as_ + lc * 4);
    }
#pragma unroll
    for (int p = 0; p < BPASS; p++) {
      int r = lr + p * RPP;
      pb[p] = *(const float4*)(bp + (long long)(n0 + r) * bs_ + lc * 4);
    }
  };

  const int tx = tid % (BN / TN);
  const int ty = tid / (BN / TN);
  float acc[TM][TN];
#pragma unroll
  for (int i = 0; i < TM; i++)
#pragma unroll
    for (int j = 0; j < TN; j++) acc[i][j] = 0.0f;

  load(0);
  for (int kt = 0; kt < nt; ++kt) {
    __syncthreads();
#pragma unroll
    for (int p = 0; p < APASS; p++) {
      int r = lr + p * RPP;
      As[lc * 4 + 0][r] = pa[p].x; As[lc * 4 + 1][r] = pa[p].y;
      As[lc * 4 + 2][r] = pa[p].z; As[lc * 4 + 3][r] = pa[p].w;
    }
#pragma unroll
    for (int p = 0; p < BPASS; p++) {
      int r = lr + p * RPP;
      Bs[lc * 4 + 0][r] = pb[p].x; Bs[lc * 4 + 1][r] = pb[p].y;
      Bs[lc * 4 + 2][r] = pb[p].z; Bs[lc * 4 + 3][r] = pb[p].w;
    }
    __syncthreads();
    if (kt + 1 < nt) load(kt + 1);
#pragma unroll
    for (int k = 0; k < BKK; k++) {
      float a[TM], b[TN];
#pragma unroll
      for (int i = 0; i < TM; i++) a[i] = As[k][ty * TM + i];
#pragma unroll
      for (int j = 0; j < TN; j++) b[j] = Bs[k][tx * TN + j];
#pragma unroll
      for (int i = 0; i < TM; i++)
#pragma unroll
        for (int j = 0; j < TN; j++) acc[i][j] += a[i] * b[j];
    }
  }

#pragma unroll
  for (int i = 0; i < TM; i++) {
    const int m = m0 + ty * TM + i;
    const int n = n0 + tx * TN;
    float v[TN];
#pragma unroll
    for (int j = 0; j < TN; j++) {
      float a = acc[i][j];
      if (EPI == 0) {
        float s = e1[n + j] * 0.999995f;
        a = (a + e0[n + j]) * s + e2[n + j];
        a = fmaxf(a, 0.0f);
      } else if (EPI == 1) {
        a = a + e0[n + j] + e1[n + j];
      } else {
        a = a + e0[(long long)m * e0rs + n + j];
      }
      v[j] = a;
    }
    float4 o; o.x = v[0]; o.y = v[1]; o.z = v[2]; o.w = v[3];
    *(float4*)(C + (long long)m * ldc + n) = o;
  }
}

__global__ __launch_bounds__(256) void gate_k(const float* __restrict__ hl,
                                              const float* __restrict__ cl,
                                              const float* __restrict__ zs,
                                              const float* __restrict__ Wg,
                                              const float* __restrict__ bg,
                                              float* __restrict__ rout, int t)
{
  const int b = blockIdx.x, tid = threadIdx.x;
  float4 h4 = *(const float4*)(hl + (long long)b * 1024 + tid * 4);
  float4 c4 = *(const float4*)(cl + (long long)b * 1024 + tid * 4);
  float4 w0h = *(const float4*)(Wg + 512 + tid * 4);
  float4 w0c = *(const float4*)(Wg + 1536 + tid * 4);
  float4 w1h = *(const float4*)(Wg + 2560 + 512 + tid * 4);
  float4 w1c = *(const float4*)(Wg + 2560 + 1536 + tid * 4);
  float z0 = h4.x * w0h.x + h4.y * w0h.y + h4.z * w0h.z + h4.w * w0h.w
           + c4.x * w0c.x + c4.y * w0c.y + c4.z * w0c.z + c4.w * w0c.w;
  float z1 = h4.x * w1h.x + h4.y * w1h.y + h4.z * w1h.z + h4.w * w1h.w
           + c4.x * w1c.x + c4.y * w1c.y + c4.z * w1c.z + c4.w * w1c.w;
  __shared__ float s0[256], s1[256];
  s0[tid] = z0; s1[tid] = z1;
  __syncthreads();
  for (int s = 128; s > 0; s >>= 1) {
    if (tid < s) { s0[tid] += s0[tid + s]; s1[tid] += s1[tid + s]; }
    __syncthreads();
  }
  if (tid == 0) {
    float zz0 = s0[0] + zs[(b * 64 + t) * 2 + 0] + bg[0];
    float zz1 = s1[0] + zs[(b * 64 + t) * 2 + 1] + bg[1];
    int idx = (zz1 > zz0) ? 1 : 0;
    rout[b * 2 + 0] = (idx == 0) ? 1.0f : 0.0f;
    rout[b * 2 + 1] = (idx == 1) ? 1.0f : 0.0f;
  }
}

__global__ __launch_bounds__(256) void upd_small_k(const float* __restrict__ g,
                                                   const float* __restrict__ c_old,
                                                   float* __restrict__ h_new,
                                                   float* __restrict__ c_new)
{
  const int idx = blockIdx.x * 256 + threadIdx.x;
  const int b = idx >> 9, n = idx & 511;
  const float* gb = g + (long long)b * 2048;
  float gi = gb[n], gf = gb[512 + n], gg = gb[1024 + n], go = gb[1536 + n];
  float c2 = sigf(gf) * c_old[idx] + sigf(gi) * tanhf(gg);
  float h2 = sigf(go) * tanhf(c2);
  c_new[idx] = c2; h_new[idx] = h2;
}

__global__ __launch_bounds__(256) void upd_large_k(const float* __restrict__ g,
                                                   const float* __restrict__ h_old,
                                                   const float* __restrict__ c_old,
                                                   const float* __restrict__ hs_new,
                                                   const float* __restrict__ cs_new,
                                                   const float* __restrict__ r,
                                                   float* __restrict__ h_new,
                                                   float* __restrict__ c_new)
{
  const int idx = blockIdx.x * 256 + threadIdx.x;
  const int b = idx >> 10, n = idx & 1023;
  const float* gb = g + (long long)b * 4096;
  float gi = gb[n], gf = gb[1024 + n], gg = gb[2048 + n], go = gb[3072 + n];
  float cln = sigf(gf) * c_old[idx] + sigf(gi) * tanhf(gg);
  float hln = sigf(go) * tanhf(cln);
  float ph = (n < 512) ? hs_new[b * 512 + n] : h_old[idx];
  float pc = (n < 512) ? cs_new[b * 512 + n] : c_old[idx];
  float r0 = r[b * 2], r1 = r[b * 2 + 1];
  h_new[idx] = r0 * hln + r1 * ph;
  c_new[idx] = r0 * cln + r1 * pc;
}

// ===========================================================================
extern "C" void kernel_launch(void* const* d_in, const int* in_sizes, int n_in,
                              void* d_out, int out_size, void* d_ws, size_t ws_size,
                              hipStream_t stream)
{
  const float* x     = (const float*)d_in[0];
  const float* xs    = (const float*)d_in[1];
  const float* W_p   = (const float*)d_in[2];
  const float* b_p   = (const float*)d_in[3];
  const float* g_p   = (const float*)d_in[4];
  const float* be_p  = (const float*)d_in[5];
  const float* W_s   = (const float*)d_in[6];
  const float* b_s   = (const float*)d_in[7];
  const float* g_s   = (const float*)d_in[8];
  const float* be_s  = (const float*)d_in[9];
  const float* Wih_l = (const float*)d_in[10];
  const float* Whh_l = (const float*)d_in[11];
  const float* bih_l = (const float*)d_in[12];
  const float* bhh_l = (const float*)d_in[13];
  const float* Wih_s = (const float*)d_in[14];
  const float* Whh_s = (const float*)d_in[15];
  const float* bih_s = (const float*)d_in[16];
  const float* bhh_s = (const float*)d_in[17];
  const float* W_g   = (const float*)d_in[18];
  const float* b_g   = (const float*)d_in[19];
  const float* W_c   = (const float*)d_in[20];
  const float* b_c   = (const float*)d_in[21];
  float* out = (float*)d_out;

  const int BT = 16384;
  const size_t NEED_MFMA = 753401856ULL;   // bytes, see layout below

  if (ws_size >= NEED_MFMA) {
    // ---------------- MFMA f16-split path ----------------
    char* base = (char*)d_ws;
    size_t off = 0;
    auto alloc = [&](size_t bytes) { void* p = base + off; off += bytes; return p; };
    f16* x_h   = (f16*)alloc((size_t)BT * 2048 * 2);
    f16* x_l   = (f16*)alloc((size_t)BT * 2048 * 2);
    f16* xs_h  = (f16*)alloc((size_t)BT * 1280 * 2);
    f16* xs_l  = (f16*)alloc((size_t)BT * 1280 * 2);
    f16* Wp_h  = (f16*)alloc((size_t)2048 * 2048 * 2);
    f16* Wp_l  = (f16*)alloc((size_t)2048 * 2048 * 2);
    f16* Ws_h  = (f16*)alloc((size_t)512 * 1280 * 2);
    f16* Ws_l  = (f16*)alloc((size_t)512 * 1280 * 2);
    f16* Wil_h = (f16*)alloc((size_t)4096 * 2560 * 2);
    f16* Wil_l = (f16*)alloc((size_t)4096 * 2560 * 2);
    f16* Wis_h = (f16*)alloc((size_t)2048 * 512 * 2);
    f16* Wis_l = (f16*)alloc((size_t)2048 * 512 * 2);
    f16* fe_h  = (f16*)alloc((size_t)BT * 2048 * 2);
    f16* fe_l  = (f16*)alloc((size_t)BT * 2048 * 2);
    float* sfeats = (float*)alloc((size_t)BT * 512 * 4);
    f16* sf_h  = (f16*)alloc((size_t)BT * 512 * 2);
    f16* sf_l  = (f16*)alloc((size_t)BT * 512 * 2);
    float* Gx_l = (float*)alloc((size_t)BT * 4096 * 4);
    // aliased regions (sources dead by the time these are written):
    float* Gx_s = (float*)x_h;                    // 134.2 MB == x_h+x_l exactly
    char* xsr = (char*)xs_h;                      // xs region -> states etc.
    float* zs  = (float*)xsr;                     xsr += (size_t)BT * 2 * 4;
    float* gates_l = (float*)xsr;                 xsr += (size_t)256 * 4096 * 4;
    float* gates_s = (float*)xsr;                 xsr += (size_t)256 * 2048 * 4;
    float* hl[2] = {(float*)xsr, (float*)(xsr + 1048576)};  xsr += 2097152;
    float* cl[2] = {(float*)xsr, (float*)(xsr + 1048576)};  xsr += 2097152;
    float* hsb[2] = {(float*)xsr, (float*)(xsr + 524288)};  xsr += 1048576;
    float* csb[2] = {(float*)xsr, (float*)(xsr + 524288)};  xsr += 1048576;

    // splits
    split_k4<<<32768, 256, 0, stream>>>((const float4*)x,     (f16x4*)x_h,  (f16x4*)x_l,  BT * 2048 / 4);
    split_k4<<<20480, 256, 0, stream>>>((const float4*)xs,    (f16x4*)xs_h, (f16x4*)xs_l, BT * 1280 / 4);
    split_k4<<<4096,  256, 0, stream>>>((const float4*)W_p,   (f16x4*)Wp_h, (f16x4*)Wp_l, 2048 * 2048 / 4);
    split_k4<<<640,   256, 0, stream>>>((const float4*)W_s,   (f16x4*)Ws_h, (f16x4*)Ws_l, 512 * 1280 / 4);
    split_k4<<<10240, 256, 0, stream>>>((const float4*)Wih_l, (f16x4*)Wil_h,(f16x4*)Wil_l,4096 * 2560 / 4);
    split_k4<<<1024,  256, 0, stream>>>((const float4*)Wih_s, (f16x4*)Wis_h,(f16x4*)Wis_l,2048 * 512 / 4);

    // feats (f16 split only) = BN_ReLU(x @ W_p^T + b_p)
    gemm_mfma<0><<<dim3(128, 16), 256, 0, stream>>>(
        x_h, x_l, 2048, 2048, nullptr, nullptr, 0, 0,
        Wp_h, Wp_l, 2048,
        nullptr, fe_h, fe_l, 2048, b_p, g_p, be_p);
    // sfeats (f32 + f16 split)
    gemm_mfma<0><<<dim3(128, 4), 256, 0, stream>>>(
        xs_h, xs_l, 1280, 1280, nullptr, nullptr, 0, 0,
        Ws_h, Ws_l, 1280,
        sfeats, sf_h, sf_l, 512, b_s, g_s, be_s);
    zs_k<<<BT / 4, 256, 0, stream>>>(sfeats, W_g, zs);
    // Gx_l = [feats|sfeats] @ Wih_l^T + bih_l + bhh_l
    gemm_mfma<1><<<dim3(128, 32), 256, 0, stream>>>(
        fe_h, fe_l, 2048, 2048, sf_h, sf_l, 512, 512,
        Wil_h, Wil_l, 2560,
        Gx_l, nullptr, nullptr, 4096, bih_l, bhh_l, nullptr);
    // Gx_s = sfeats @ Wih_s^T + bih_s + bhh_s   (writes over dead x_h/x_l)
    gemm_mfma<1><<<dim3(128, 16), 256, 0, stream>>>(
        sf_h, sf_l, 512, 512, nullptr, nullptr, 0, 0,
        Wis_h, Wis_l, 512,
        Gx_s, nullptr, nullptr, 2048, bih_s, bhh_s, nullptr);

    hipMemsetAsync(hl[0], 0, 1048576, stream);
    hipMemsetAsync(cl[0], 0, 1048576, stream);
    hipMemsetAsync(hsb[0], 0, 524288, stream);
    hipMemsetAsync(csb[0], 0, 524288, stream);

    for (int t = 0; t < 64; ++t) {
      const int o = t & 1, nw = o ^ 1;
      step_gemm<<<dim3(4, 96), 256, 0, stream>>>(
          hl[o], hsb[o], Whh_l, Whh_s,
          Gx_l + (long long)t * 4096, Gx_s + (long long)t * 2048,
          gates_l, gates_s);
      step_upd<<<256, 256, 0, stream>>>(
          gates_l, gates_s, hl[o], cl[o], csb[o],
          hl[nw], cl[nw], hsb[nw], csb[nw],
          zs, W_g, b_g, out + 61184 + (long long)t * 512, t);
    }
    logits_k<<<256, 256, 0, stream>>>(hl[0], W_c, b_c, out);
    return;
  }

  // ---------------- Round-1 all-f32 fallback ----------------
  float* ws = (float*)d_ws;
  size_t off = 0;
  auto alloc = [&](size_t n) { float* p = ws + off; off += n; return p; };
  float* feats   = alloc((size_t)BT * 2048);
  float* sfeats  = alloc((size_t)BT * 512);
  float* zs      = alloc((size_t)BT * 2);
  float* gates_l = alloc((size_t)256 * 4096);
  float* gates_s = alloc((size_t)256 * 2048);
  float* hl[2] = { alloc(256 * 1024), alloc(256 * 1024) };
  float* cl[2] = { alloc(256 * 1024), alloc(256 * 1024) };
  float* hsb[2] = { alloc(256 * 512),  alloc(256 * 512) };
  float* csb[2] = { alloc(256 * 512),  alloc(256 * 512) };
  const size_t base_floats = off;
  float* Gx_l = nullptr; float* Gx_s = nullptr;
  const size_t full_floats = base_floats + (size_t)BT * 4096 + (size_t)BT * 2048;
  const bool precomp = ws_size >= full_floats * sizeof(float);
  if (precomp) {
    Gx_l = alloc((size_t)BT * 4096);
    Gx_s = alloc((size_t)BT * 2048);
  }

  hipMemsetAsync(hl[0], 0, 256 * 1024 * sizeof(float), stream);
  hipMemsetAsync(cl[0], 0, 256 * 1024 * sizeof(float), stream);
  hipMemsetAsync(hsb[0], 0, 256 * 512 * sizeof(float), stream);
  hipMemsetAsync(csb[0], 0, 256 * 512 * sizeof(float), stream);

  gemm_nt<128, 64, 8, 4, 0><<<dim3(BT / 128, 2048 / 64), 256, 0, stream>>>(
      BT, 2048, x, 2048, W_p, 2048, 2048,
      nullptr, 0, nullptr, 0, 0, nullptr, 0, nullptr, 0, 0,
      feats, 2048, b_p, g_p, be_p, 0);
  gemm_nt<128, 64, 8, 4, 0><<<dim3(BT / 128, 512 / 64), 256, 0, stream>>>(
      BT, 512, xs, 1280, W_s, 1280, 1280,
      nullptr, 0, nullptr, 0, 0, nullptr, 0, nullptr, 0, 0,
      sfeats, 512, b_s, g_s, be_s, 0);
  zs_k<<<BT / 4, 256, 0, stream>>>(sfeats, W_g, zs);

  if (precomp) {
    gemm_nt<128, 64, 8, 4, 1><<<dim3(BT / 128, 4096 / 64), 256, 0, stream>>>(
        BT, 4096, feats, 2048, Wih_l, 2560, 2048,
        sfeats, 512, Wih_l + 2048, 2560, 512, nullptr, 0, nullptr, 0, 0,
        Gx_l, 4096, bih_l, bhh_l, nullptr, 0);
    gemm_nt<128, 64, 8, 4, 1><<<dim3(BT / 128, 2048 / 64), 256, 0, stream>>>(
        BT, 2048, sfeats, 512, Wih_s, 512, 512,
        nullptr, 0, nullptr, 0, 0, nullptr, 0, nullptr, 0, 0,
        Gx_s, 2048, bih_s, bhh_s, nullptr, 0);
  }

  for (int t = 0; t < 64; ++t) {
    const int o = t & 1, nw = o ^ 1;
    if (precomp) {
      gemm_nt<64, 64, 4, 4, 2><<<dim3(4, 2048 / 64), 256, 0, stream>>>(
          256, 2048, hsb[o], 512, Whh_s, 512, 512,
          nullptr, 0, nullptr, 0, 0, nullptr, 0, nullptr, 0, 0,
          gates_s, 2048, Gx_s + (long long)t * 2048, nullptr, nullptr, 64LL * 2048);
    } else {
      gemm_nt<64, 64, 4, 4, 1><<<dim3(4, 2048 / 64), 256, 0, stream>>>(
          256, 2048, sfeats + (long long)t * 512, 64LL * 512, Wih_s, 512, 512,
          hsb[o], 512, Whh_s, 512, 512, nullptr, 0, nullptr, 0, 0,
          gates_s, 2048, bih_s, bhh_s, nullptr, 0);
    }
    upd_small_k<<<512, 256, 0, stream>>>(gates_s, csb[o], hsb[nw], csb[nw]);
    gate_k<<<256, 256, 0, stream>>>(hl[o], cl[o], zs, W_g, b_g,
                                    out + 61184 + (long long)t * 512, t);
    if (precomp) {
      gemm_nt<64, 64, 4, 4, 2><<<dim3(4, 4096 / 64), 256, 0, stream>>>(
          256, 4096, hl[o], 1024, Whh_l, 1024, 1024,
          nullptr, 0, nullptr, 0, 0, nullptr, 0, nullptr, 0, 0,
          gates_l, 4096, Gx_l + (long long)t * 4096, nullptr, nullptr, 64LL * 4096);
    } else {
      gemm_nt<64, 64, 4, 4, 1><<<dim3(4, 4096 / 64), 256, 0, stream>>>(
          256, 4096, feats + (long long)t * 2048, 64LL * 2048, Wih_l, 2560, 2048,
          sfeats + (long long)t * 512, 64LL * 512, Wih_l + 2048, 2560, 512,
          hl[o], 1024, Whh_l, 1024, 1024,
          gates_l, 4096, bih_l, bhh_l, nullptr, 0);
    }
    upd_large_k<<<1024, 256, 0, stream>>>(gates_l, hl[o], cl[o], hsb[nw], csb[nw],
                                          out + 61184 + (long long)t * 512,
                                          hl[nw], cl[nw]);
  }
  logits_k<<<256, 256, 0, stream>>>(hl[0], W_c, b_c, out);
}

// Round 3
// 9375.352 us; speedup vs baseline: 1.7400x; 1.7397x over previous
//
#include <hip/hip_runtime.h>
#include <math.h>

// ---------------------------------------------------------------------------
// LiteEval gated dual-LSTM.  Round 3.
//  * f16 hi/lo split MFMA GEMMs (3 MFMA per frag, f32 accum, ~f32 accuracy)
//    for ALL matmuls incl. the per-step recurrent ones.
//  * Workspace-adaptive: time axis chunked (T' in {64..1}); Gx_l/Gx_s/feats
//    exist only for the current chunk (time-major rows rr = tt*256 + b).
//    Floor ~141 MB (R2 needed 753 MB and never ran -> ws_size < 753 MB).
//  * Fragment-order LDS staging (pre-swizzled global source, m173 pattern):
//    conflict-free ds_read_b128 fragment loads AND conflict-free staging.
//  * Fallback: Round-1 all-f32 non-precomp path (ws < floor) - proven at 16.3ms.
// ---------------------------------------------------------------------------

typedef _Float16 f16;
typedef _Float16 f16x4 __attribute__((ext_vector_type(4)));
typedef _Float16 f16x8 __attribute__((ext_vector_type(8)));
typedef float f32x4 __attribute__((ext_vector_type(4)));

__device__ __forceinline__ float sigf(float x) { return 1.0f / (1.0f + expf(-x)); }

__device__ __forceinline__ void gload16(const f16* g, f16* l) {
  __builtin_amdgcn_global_load_lds((const __attribute__((address_space(1))) void*)g,
                                   (__attribute__((address_space(3))) void*)l, 16, 0, 0);
}

// split f32 -> f16 hi + f16 lo (4 elems/thread)
__global__ __launch_bounds__(256) void split_k4(const float4* __restrict__ in,
                                                f16x4* __restrict__ hi,
                                                f16x4* __restrict__ lo, int n4)
{
  int i = blockIdx.x * 256 + threadIdx.x;
  if (i >= n4) return;
  float4 v = in[i];
  f16x4 h, l;
  h[0] = (f16)v.x; l[0] = (f16)(v.x - (float)h[0]);
  h[1] = (f16)v.y; l[1] = (f16)(v.y - (float)h[1]);
  h[2] = (f16)v.z; l[2] = (f16)(v.z - (float)h[2]);
  h[3] = (f16)v.w; l[3] = (f16)(v.w - (float)h[3]);
  hi[i] = h; lo[i] = l;
}

// ---------------------------------------------------------------------------
// Split-MFMA GEMM core.  Tile BM=128 x BN, BK=32, 256 threads = 4 waves
// (2x2 over tile).  C[m][n] = sum_k A[m][k]*B[n][k].
// SPLITA: A is f32, reg-staged with on-the-fly hi/lo split (1 segment).
// !SPLITA: A presplit f16 hi/lo (up to 2 K-segments), gload16 staging with
//          fragment-order per-lane global source.
// Row map (per A segment): map ? global_row = (r&255)*64 + t0 + (r>>8) : r.
// EPI 0: relu((v+e0)*e1*s+e2) -> f16 hi/lo (Ch,Cl)
// EPI 1: v+e0+e1 -> f32 C
// EPI 2: v+G[row*ldc+col] -> f32 C
template <int BN, int EPI, bool SPLITA>
__device__ __forceinline__ void gmm_core(
    int m0, int n0, int t0,
    const float* __restrict__ A32,
    const f16* __restrict__ A0h, const f16* __restrict__ A0l, int lda0, int K0, int map0,
    const f16* __restrict__ A1h, const f16* __restrict__ A1l, int lda1, int K1, int map1,
    const f16* __restrict__ Bh, const f16* __restrict__ Bl, int ldb,
    float* __restrict__ C, f16* __restrict__ Ch, f16* __restrict__ Cl, int ldc,
    const float* __restrict__ e0, const float* __restrict__ e1,
    const float* __restrict__ e2, const float* __restrict__ G)
{
  constexpr int NF  = BN / 32;   // B frags per wave-column
  constexpr int NBF = BN / 16;   // B frags total
  __shared__ f16 sAh[128 * 32], sAl[128 * 32], sBh[BN * 32], sBl[BN * 32];
  const int tid = threadIdx.x;
  const int w = tid >> 6, lane = tid & 63;
  const int wr = w >> 1, wc = w & 1;
  const int fr = lane & 15, fq = lane >> 4;

  f32x4 acc[4][NF];
#pragma unroll
  for (int m = 0; m < 4; ++m)
#pragma unroll
    for (int n = 0; n < NF; ++n) acc[m][n] = (f32x4){0.f, 0.f, 0.f, 0.f};

  const int nt = (K0 + K1) >> 5;

  const float* rp32[8];
  const f16* rpa[8];
  const f16* rpb[NBF];
  const int kcol = fq << 3;
  if (SPLITA) {
    if (tid < 128) {
      const int lf = tid >> 1, hf = tid & 1;
      const int cc = ((lf >> 4) << 3) + hf * 4;
#pragma unroll
      for (int j = 0; j < 8; ++j) {
        int r = m0 + ((j >> 2) << 6) + ((j & 3) << 4) + (lf & 15);
        int rg = map0 ? (((r & 255) << 6) + t0 + (r >> 8)) : r;
        rp32[j] = A32 + (long long)rg * lda0 + cc;
      }
    }
  } else {
    if (w < 2) {
#pragma unroll
      for (int j = 0; j < 8; ++j) {
        int r = m0 + ((j >> 2) << 6) + ((j & 3) << 4) + fr;
        int rg = map0 ? (((r & 255) << 6) + t0 + (r >> 8)) : r;
        rpa[j] = ((w == 0) ? A0h : A0l) + (long long)rg * lda0 + kcol;
      }
    }
  }
  if (w >= 2) {
#pragma unroll
    for (int j = 0; j < NBF; ++j) {
      int r = n0 + (j / NF) * (BN / 2) + (j % NF) * 16 + fr;
      rpb[j] = ((w == 2) ? Bh : Bl) + (long long)r * ldb + kcol;
    }
  }

  for (int kt = 0; kt < nt; ++kt) {
    const int kg = kt << 5;
    if (!SPLITA && K1 > 0 && kg == K0 && w < 2) {
#pragma unroll
      for (int j = 0; j < 8; ++j) {
        int r = m0 + ((j >> 2) << 6) + ((j & 3) << 4) + fr;
        int rg = map1 ? (((r & 255) << 6) + t0 + (r >> 8)) : r;
        rpa[j] = ((w == 0) ? A1h : A1l) + (long long)rg * lda1 + kcol - K0;
      }
    }
    // ---- stage
    if (SPLITA) {
      if (tid < 128) {
#pragma unroll
        for (int j = 0; j < 8; ++j) {
          float4 v = *(const float4*)(rp32[j] + kg);
          f16x4 h, l;
          h[0] = (f16)v.x; l[0] = (f16)(v.x - (float)h[0]);
          h[1] = (f16)v.y; l[1] = (f16)(v.y - (float)h[1]);
          h[2] = (f16)v.z; l[2] = (f16)(v.z - (float)h[2]);
          h[3] = (f16)v.w; l[3] = (f16)(v.w - (float)h[3]);
          *(f16x4*)((char*)sAh + (j << 10) + (tid << 3)) = h;
          *(f16x4*)((char*)sAl + (j << 10) + (tid << 3)) = l;
        }
      } else {
        f16* dst = (w == 2) ? sBh : sBl;
#pragma unroll
        for (int j = 0; j < NBF; ++j) gload16(rpb[j] + kg, dst + j * 512);
      }
    } else {
      if (w < 2) {
        f16* dst = (w == 0) ? sAh : sAl;
#pragma unroll
        for (int j = 0; j < 8; ++j) gload16(rpa[j] + kg, dst + j * 512);
      } else {
        f16* dst = (w == 2) ? sBh : sBl;
#pragma unroll
        for (int j = 0; j < NBF; ++j) gload16(rpb[j] + kg, dst + j * 512);
      }
    }
    __syncthreads();
    // ---- compute (lane-linear fragment reads; conflict-free)
    f16x8 vbh[NF], vbl[NF];
#pragma unroll
    for (int n = 0; n < NF; ++n) {
      vbh[n] = *(const f16x8*)&sBh[(wc * NF + n) * 512 + lane * 8];
      vbl[n] = *(const f16x8*)&sBl[(wc * NF + n) * 512 + lane * 8];
    }
#pragma unroll
    for (int m = 0; m < 4; ++m) {
      f16x8 ah = *(const f16x8*)&sAh[(wr * 4 + m) * 512 + lane * 8];
      f16x8 al = *(const f16x8*)&sAl[(wr * 4 + m) * 512 + lane * 8];
#pragma unroll
      for (int n = 0; n < NF; ++n) {
        acc[m][n] = __builtin_amdgcn_mfma_f32_16x16x32_f16(ah, vbh[n], acc[m][n], 0, 0, 0);
        acc[m][n] = __builtin_amdgcn_mfma_f32_16x16x32_f16(ah, vbl[n], acc[m][n], 0, 0, 0);
        acc[m][n] = __builtin_amdgcn_mfma_f32_16x16x32_f16(al, vbh[n], acc[m][n], 0, 0, 0);
      }
    }
    __syncthreads();
  }

  // ---- epilogue: D mapping col=fr, row=fq*4+reg
#pragma unroll
  for (int m = 0; m < 4; ++m) {
#pragma unroll
    for (int n = 0; n < NF; ++n) {
      const int col = n0 + wc * (NF * 16) + n * 16 + fr;
      float p0 = 0.f, p1 = 0.f, p2 = 0.f;
      if (EPI == 0) { p0 = e0[col]; p1 = e1[col] * 0.99999500003750f; p2 = e2[col]; }
      else if (EPI == 1) { p0 = e0[col] + e1[col]; }
#pragma unroll
      for (int r = 0; r < 4; ++r) {
        const int row = m0 + wr * 64 + m * 16 + fq * 4 + r;
        const long long idx = (long long)row * ldc + col;
        float v = acc[m][n][r];
        if (EPI == 0) {
          v = fmaxf((v + p0) * p1 + p2, 0.f);
          f16 h = (f16)v;
          Ch[idx] = h; Cl[idx] = (f16)(v - (float)h);
        } else if (EPI == 1) {
          C[idx] = v + p0;
        } else {
          C[idx] = v + G[idx];
        }
      }
    }
  }
}

template <int EPI, bool SPLITA>
__global__ __launch_bounds__(256) void gmm(
    int t0,
    const float* __restrict__ A32,
    const f16* __restrict__ A0h, const f16* __restrict__ A0l, int lda0, int K0, int map0,
    const f16* __restrict__ A1h, const f16* __restrict__ A1l, int lda1, int K1, int map1,
    const f16* __restrict__ Bh, const f16* __restrict__ Bl, int ldb,
    float* __restrict__ C, f16* __restrict__ Ch, f16* __restrict__ Cl, int ldc,
    const float* __restrict__ e0, const float* __restrict__ e1,
    const float* __restrict__ e2)
{
  gmm_core<128, EPI, SPLITA>(blockIdx.x * 128, blockIdx.y * 128, t0,
      A32, A0h, A0l, lda0, K0, map0, A1h, A1l, lda1, K1, map1,
      Bh, Bl, ldb, C, Ch, Cl, ldc, e0, e1, e2, nullptr);
}

// routed per-step recurrent GEMM: y<64 -> large (N=4096,K=1024),
// y>=64 -> small (N=2048,K=512).  gates = h @ Whh^T + Gx[t]
__global__ __launch_bounds__(256) void step_g(
    const float* __restrict__ hl, const float* __restrict__ hs,
    const f16* __restrict__ Whl_h, const f16* __restrict__ Whl_l,
    const f16* __restrict__ Whs_h, const f16* __restrict__ Whs_l,
    const float* __restrict__ Gl, const float* __restrict__ Gs,
    float* __restrict__ gl, float* __restrict__ gs)
{
  const bool big = blockIdx.y < 64;
  const int ny = big ? blockIdx.y : (blockIdx.y - 64);
  gmm_core<64, 2, true>(
      blockIdx.x * 128, ny * 64, 0,
      big ? hl : hs, nullptr, nullptr, big ? 1024 : 512, big ? 1024 : 512, 0,
      nullptr, nullptr, 0, 0, 0,
      big ? Whl_h : Whs_h, big ? Whl_l : Whs_l, big ? 1024 : 512,
      big ? gl : gs, nullptr, nullptr, big ? 4096 : 2048,
      nullptr, nullptr, nullptr, big ? Gl : Gs);
}

// zs[bt,g] = sfeats[bt,:] . W_g[g,:512]  from split sfeats
__global__ __launch_bounds__(256) void zs_split_k(const f16* __restrict__ sfh,
                                                  const f16* __restrict__ sfl,
                                                  const float* __restrict__ Wg,
                                                  float* __restrict__ zs)
{
  const int wave = threadIdx.x >> 6, lane = threadIdx.x & 63;
  const int row = blockIdx.x * 4 + wave;
  f16x8 h8 = *(const f16x8*)(sfh + (long long)row * 512 + lane * 8);
  f16x8 l8 = *(const f16x8*)(sfl + (long long)row * 512 + lane * 8);
  const float* w0 = Wg + lane * 8;
  const float* w1 = Wg + 2560 + lane * 8;
  float z0 = 0.f, z1 = 0.f;
#pragma unroll
  for (int i = 0; i < 8; ++i) {
    float s = (float)h8[i] + (float)l8[i];
    z0 += s * w0[i]; z1 += s * w1[i];
  }
#pragma unroll
  for (int off = 32; off > 0; off >>= 1) {
    z0 += __shfl_down(z0, off);
    z1 += __shfl_down(z1, off);
  }
  if (lane == 0) { zs[row * 2] = z0; zs[row * 2 + 1] = z1; }
}

// fused per-step update: gate argmax + small-cell update + large-cell blend.
__global__ __launch_bounds__(256) void step_upd(
    const float* __restrict__ gl, const float* __restrict__ gs,
    const float* __restrict__ hl_o, const float* __restrict__ cl_o,
    const float* __restrict__ cs_o,
    float* __restrict__ hl_n, float* __restrict__ cl_n,
    float* __restrict__ hs_n, float* __restrict__ cs_n,
    const float* __restrict__ zs, const float* __restrict__ Wg,
    const float* __restrict__ bg, float* __restrict__ rout, int t)
{
  const int b = blockIdx.x, tid = threadIdx.x;
  __shared__ float red0[256], red1[256];
  __shared__ float shs[512], scs[512];
  __shared__ float rsh[2];

  float4 h4 = *(const float4*)(hl_o + (long long)b * 1024 + tid * 4);
  float4 c4 = *(const float4*)(cl_o + (long long)b * 1024 + tid * 4);
  float4 w0h = *(const float4*)(Wg + 512 + tid * 4);
  float4 w0c = *(const float4*)(Wg + 1536 + tid * 4);
  float4 w1h = *(const float4*)(Wg + 2560 + 512 + tid * 4);
  float4 w1c = *(const float4*)(Wg + 2560 + 1536 + tid * 4);
  red0[tid] = h4.x * w0h.x + h4.y * w0h.y + h4.z * w0h.z + h4.w * w0h.w
            + c4.x * w0c.x + c4.y * w0c.y + c4.z * w0c.z + c4.w * w0c.w;
  red1[tid] = h4.x * w1h.x + h4.y * w1h.y + h4.z * w1h.z + h4.w * w1h.w
            + c4.x * w1c.x + c4.y * w1c.y + c4.z * w1c.z + c4.w * w1c.w;

  {
    const float* gb = gs + (long long)b * 2048;
#pragma unroll
    for (int e = 0; e < 2; ++e) {
      const int n = tid * 2 + e;
      float gi = gb[n], gf = gb[512 + n], gg = gb[1024 + n], go = gb[1536 + n];
      float c2 = sigf(gf) * cs_o[b * 512 + n] + sigf(gi) * tanhf(gg);
      float h2 = sigf(go) * tanhf(c2);
      shs[n] = h2; scs[n] = c2;
      hs_n[b * 512 + n] = h2; cs_n[b * 512 + n] = c2;
    }
  }
  __syncthreads();
  for (int s = 128; s > 0; s >>= 1) {
    if (tid < s) { red0[tid] += red0[tid + s]; red1[tid] += red1[tid + s]; }
    __syncthreads();
  }
  if (tid == 0) {
    float z0 = red0[0] + zs[(b * 64 + t) * 2 + 0] + bg[0];
    float z1 = red1[0] + zs[(b * 64 + t) * 2 + 1] + bg[1];
    int hard = (z1 > z0) ? 1 : 0;   // jnp.argmax ties -> 0
    rsh[0] = hard ? 0.0f : 1.0f; rsh[1] = hard ? 1.0f : 0.0f;
    rout[b * 2 + 0] = rsh[0]; rout[b * 2 + 1] = rsh[1];
  }
  __syncthreads();
  const float r0 = rsh[0], r1 = rsh[1];

  {
    const float* glb = gl + (long long)b * 4096;
    const int n = tid * 4;
    float4 gi4 = *(const float4*)(glb + n);
    float4 gf4 = *(const float4*)(glb + 1024 + n);
    float4 gg4 = *(const float4*)(glb + 2048 + n);
    float4 go4 = *(const float4*)(glb + 3072 + n);
    float4 co4 = *(const float4*)(cl_o + (long long)b * 1024 + n);
    float4 ho4 = *(const float4*)(hl_o + (long long)b * 1024 + n);
    float gi[4] = {gi4.x, gi4.y, gi4.z, gi4.w};
    float gf[4] = {gf4.x, gf4.y, gf4.z, gf4.w};
    float gg[4] = {gg4.x, gg4.y, gg4.z, gg4.w};
    float go[4] = {go4.x, go4.y, go4.z, go4.w};
    float co[4] = {co4.x, co4.y, co4.z, co4.w};
    float ho[4] = {ho4.x, ho4.y, ho4.z, ho4.w};
    float hv[4], cv[4];
#pragma unroll
    for (int e = 0; e < 4; ++e) {
      float cln = sigf(gf[e]) * co[e] + sigf(gi[e]) * tanhf(gg[e]);
      float hln = sigf(go[e]) * tanhf(cln);
      float ph = (n + e < 512) ? shs[n + e] : ho[e];
      float pc = (n + e < 512) ? scs[n + e] : co[e];
      hv[e] = r0 * hln + r1 * ph;
      cv[e] = r0 * cln + r1 * pc;
    }
    float4 hw = {hv[0], hv[1], hv[2], hv[3]};
    float4 cw = {cv[0], cv[1], cv[2], cv[3]};
    *(float4*)(hl_n + (long long)b * 1024 + n) = hw;
    *(float4*)(cl_n + (long long)b * 1024 + n) = cw;
  }
}

// logits = h_l @ W_c^T + b_c
__global__ __launch_bounds__(256) void logits_k(const float* __restrict__ hl,
                                                const float* __restrict__ Wc,
                                                const float* __restrict__ bc,
                                                float* __restrict__ out)
{
  __shared__ float hsd[1024];
  const int b = blockIdx.x, tid = threadIdx.x;
  *(float4*)(hsd + tid * 4) = *(const float4*)(hl + (long long)b * 1024 + tid * 4);
  __syncthreads();
  if (tid < 239) {
    const float* w = Wc + (long long)tid * 1024;
    float s = 0.0f;
    for (int k = 0; k < 1024; k += 4) {
      float4 wv = *(const float4*)(w + k);
      s += hsd[k] * wv.x + hsd[k + 1] * wv.y + hsd[k + 2] * wv.z + hsd[k + 3] * wv.w;
    }
    out[(long long)b * 239 + tid] = s + bc[tid];
  }
}

// ===========================================================================
// Round-1 all-f32 fallback kernels (non-precomp path; proven correct).
#define BKK 32
template <int BM, int BN, int TM, int TN, int EPI>
__global__ __launch_bounds__(256) void gemm_nt(
    int M, int N,
    const float* __restrict__ A0, long long as0, const float* __restrict__ B0, long long bs0, int K0,
    const float* __restrict__ A1, long long as1, const float* __restrict__ B1, long long bs1, int K1,
    const float* __restrict__ A2, long long as2, const float* __restrict__ B2, long long bs2, int K2,
    float* __restrict__ C, long long ldc,
    const float* __restrict__ e0, const float* __restrict__ e1, const float* __restrict__ e2)
{
  __shared__ float As[BKK][BM + 4];
  __shared__ float Bs[BKK][BN + 4];
  const int tid = threadIdx.x;
  const int m0 = blockIdx.x * BM;
  const int n0 = blockIdx.y * BN;
  constexpr int C4 = BKK / 4;
  constexpr int RPP = 256 / C4;
  constexpr int APASS = BM / RPP;
  constexpr int BPASS = BN / RPP;
  const int lr = tid / C4;
  const int lc = tid % C4;
  float4 pa[APASS], pb[BPASS];
  const int nt = (K0 + K1 + K2) / BKK;
  auto load = [&](int kt) {
    const int kg = kt * BKK;
    const float* ap; long long as_; const float* bp; long long bs_;
    if (kg < K0)           { ap = A0 + kg;          as_ = as0; bp = B0 + kg;          bs_ = bs0; }
    else if (kg < K0 + K1) { int kl = kg - K0;      ap = A1 + kl; as_ = as1; bp = B1 + kl; bs_ = bs1; }
    else                   { int kl = kg - K0 - K1; ap = A2 + kl; as_ = as2; bp = B2 + kl; bs_ = bs2; }
#pragma unroll
    for (int p = 0; p < APASS; p++) {
      int r = lr + p * RPP;
      pa[p] = *(const float4*)(ap + (long long)(m0 + r) * as_ + lc * 4);
    }
#pragma unroll
    for (int p = 0; p < BPASS; p++) {
      int r = lr + p * RPP;
      pb[p] = *(const float4*)(bp + (long long)(n0 + r) * bs_ + lc * 4);
    }
  };
  const int tx = tid % (BN / TN);
  const int ty = tid / (BN / TN);
  float acc[TM][TN];
#pragma unroll
  for (int i = 0; i < TM; i++)
#pragma unroll
    for (int j = 0; j < TN; j++) acc[i][j] = 0.0f;
  load(0);
  for (int kt = 0; kt < nt; ++kt) {
    __syncthreads();
#pragma unroll
    for (int p = 0; p < APASS; p++) {
      int r = lr + p * RPP;
      As[lc * 4 + 0][r] = pa[p].x; As[lc * 4 + 1][r] = pa[p].y;
      As[lc * 4 + 2][r] = pa[p].z; As[lc * 4 + 3][r] = pa[p].w;
    }
#pragma unroll
    for (int p = 0; p < BPASS; p++) {
      int r = lr + p * RPP;
      Bs[lc * 4 + 0][r] = pb[p].x; Bs[lc * 4 + 1][r] = pb[p].y;
      Bs[lc * 4 + 2][r] = pb[p].z; Bs[lc * 4 + 3][r] = pb[p].w;
    }
    __syncthreads();
    if (kt + 1 < nt) load(kt + 1);
#pragma unroll
    for (int k = 0; k < BKK; k++) {
      float a[TM], b[TN];
#pragma unroll
      for (int i = 0; i < TM; i++) a[i] = As[k][ty * TM + i];
#pragma unroll
      for (int j = 0; j < TN; j++) b[j] = Bs[k][tx * TN + j];
#pragma unroll
      for (int i = 0; i < TM; i++)
#pragma unroll
        for (int j = 0; j < TN; j++) acc[i][j] += a[i] * b[j];
    }
  }
#pragma unroll
  for (int i = 0; i < TM; i++) {
    const int m = m0 + ty * TM + i;
    const int n = n0 + tx * TN;
    float v[TN];
#pragma unroll
    for (int j = 0; j < TN; j++) {
      float a = acc[i][j];
      if (EPI == 0) {
        float s = e1[n + j] * 0.999995f;
        a = (a + e0[n + j]) * s + e2[n + j];
        a = fmaxf(a, 0.0f);
      } else {
        a = a + e0[n + j] + e1[n + j];
      }
      v[j] = a;
    }
    float4 o; o.x = v[0]; o.y = v[1]; o.z = v[2]; o.w = v[3];
    *(float4*)(C + (long long)m * ldc + n) = o;
  }
}

__global__ __launch_bounds__(256) void zs32_k(const float* __restrict__ sf,
                                              const float* __restrict__ Wg,
                                              float* __restrict__ zs)
{
  const int wave = threadIdx.x >> 6, lane = threadIdx.x & 63;
  const int row = blockIdx.x * 4 + wave;
  const float* s = sf + (long long)row * 512 + lane * 8;
  const float* w0 = Wg + lane * 8;
  const float* w1 = Wg + 2560 + lane * 8;
  float4 sa = *(const float4*)s, sb = *(const float4*)(s + 4);
  float4 a0 = *(const float4*)w0, b0 = *(const float4*)(w0 + 4);
  float4 a1 = *(const float4*)w1, b1 = *(const float4*)(w1 + 4);
  float z0 = sa.x * a0.x + sa.y * a0.y + sa.z * a0.z + sa.w * a0.w
           + sb.x * b0.x + sb.y * b0.y + sb.z * b0.z + sb.w * b0.w;
  float z1 = sa.x * a1.x + sa.y * a1.y + sa.z * a1.z + sa.w * a1.w
           + sb.x * b1.x + sb.y * b1.y + sb.z * b1.z + sb.w * b1.w;
#pragma unroll
  for (int off = 32; off > 0; off >>= 1) {
    z0 += __shfl_down(z0, off);
    z1 += __shfl_down(z1, off);
  }
  if (lane == 0) { zs[row * 2] = z0; zs[row * 2 + 1] = z1; }
}

// ===========================================================================
extern "C" void kernel_launch(void* const* d_in, const int* in_sizes, int n_in,
                              void* d_out, int out_size, void* d_ws, size_t ws_size,
                              hipStream_t stream)
{
  const float* x     = (const float*)d_in[0];
  const float* xs    = (const float*)d_in[1];
  const float* W_p   = (const float*)d_in[2];
  const float* b_p   = (const float*)d_in[3];
  const float* g_p   = (const float*)d_in[4];
  const float* be_p  = (const float*)d_in[5];
  const float* W_s   = (const float*)d_in[6];
  const float* b_s   = (const float*)d_in[7];
  const float* g_s   = (const float*)d_in[8];
  const float* be_s  = (const float*)d_in[9];
  const float* Wih_l = (const float*)d_in[10];
  const float* Whh_l = (const float*)d_in[11];
  const float* bih_l = (const float*)d_in[12];
  const float* bhh_l = (const float*)d_in[13];
  const float* Wih_s = (const float*)d_in[14];
  const float* Whh_s = (const float*)d_in[15];
  const float* bih_s = (const float*)d_in[16];
  const float* bhh_s = (const float*)d_in[17];
  const float* W_g   = (const float*)d_in[18];
  const float* b_g   = (const float*)d_in[19];
  const float* W_c   = (const float*)d_in[20];
  const float* b_c   = (const float*)d_in[21];
  float* out = (float*)d_out;
  float* r_out = out + 61184;            // [64][256][2]

  const int BT = 16384;

  // tier: fixed 132.8MB + 8.39MB*T'
  const size_t FIXED = 132775936ULL;
  const size_t CHUNK = 8388608ULL;
  int Tp = 0;
  for (int T = 64; T >= 1; T >>= 1)
    if (FIXED + CHUNK * (size_t)T + 65536 <= ws_size) { Tp = T; break; }

  if (Tp > 0) {
    char* base = (char*)d_ws;
    size_t off = 0;
    auto alloc = [&](size_t bytes) { void* p = base + off; off += bytes; return p; };
    f16* Wp_h  = (f16*)alloc(8388608);  f16* Wp_l  = (f16*)alloc(8388608);
    f16* Ws_h  = (f16*)alloc(1310720);  f16* Ws_l  = (f16*)alloc(1310720);
    f16* Wil_h = (f16*)alloc(20971520); f16* Wil_l = (f16*)alloc(20971520);
    f16* Wis_h = (f16*)alloc(2097152);  f16* Wis_l = (f16*)alloc(2097152);
    f16* Whl_h = (f16*)alloc(8388608);  f16* Whl_l = (f16*)alloc(8388608);
    f16* Whs_h = (f16*)alloc(2097152);  f16* Whs_l = (f16*)alloc(2097152);
    f16* sf_h  = (f16*)alloc(16777216); f16* sf_l  = (f16*)alloc(16777216);
    float* zs  = (float*)alloc(131072);
    float* hl[2] = {(float*)alloc(1048576), (float*)alloc(1048576)};
    float* cl[2] = {(float*)alloc(1048576), (float*)alloc(1048576)};
    float* hsb[2] = {(float*)alloc(524288), (float*)alloc(524288)};
    float* csb[2] = {(float*)alloc(524288), (float*)alloc(524288)};
    float* gates_l = (float*)alloc(4194304);
    float* gates_s = (float*)alloc(2097152);
    f16* feC_h = (f16*)alloc(1048576ULL * Tp);
    f16* feC_l = (f16*)alloc(1048576ULL * Tp);
    float* GxlC = (float*)alloc(4194304ULL * Tp);
    float* GxsC = (float*)alloc(2097152ULL * Tp);

    split_k4<<<4096,  256, 0, stream>>>((const float4*)W_p,   (f16x4*)Wp_h,  (f16x4*)Wp_l,  1048576);
    split_k4<<<640,   256, 0, stream>>>((const float4*)W_s,   (f16x4*)Ws_h,  (f16x4*)Ws_l,  163840);
    split_k4<<<10240, 256, 0, stream>>>((const float4*)Wih_l, (f16x4*)Wil_h, (f16x4*)Wil_l, 2621440);
    split_k4<<<1024,  256, 0, stream>>>((const float4*)Wih_s, (f16x4*)Wis_h, (f16x4*)Wis_l, 262144);
    split_k4<<<4096,  256, 0, stream>>>((const float4*)Whh_l, (f16x4*)Whl_h, (f16x4*)Whl_l, 1048576);
    split_k4<<<1024,  256, 0, stream>>>((const float4*)Whh_s, (f16x4*)Whs_h, (f16x4*)Whs_l, 262144);

    // sfeats full (split) = BN_ReLU(xs @ W_s^T + b_s)
    gmm<0, true><<<dim3(128, 4), 256, 0, stream>>>(
        0, xs, nullptr, nullptr, 1280, 1280, 0,
        nullptr, nullptr, 0, 0, 0,
        Ws_h, Ws_l, 1280,
        nullptr, sf_h, sf_l, 512, b_s, g_s, be_s);
    zs_split_k<<<4096, 256, 0, stream>>>(sf_h, sf_l, W_g, zs);

    hipMemsetAsync(hl[0], 0, 1048576, stream);
    hipMemsetAsync(cl[0], 0, 1048576, stream);
    hipMemsetAsync(hsb[0], 0, 524288, stream);
    hipMemsetAsync(csb[0], 0, 524288, stream);

    for (int t0 = 0; t0 < 64; t0 += Tp) {
      gmm<0, true><<<dim3(2 * Tp, 16), 256, 0, stream>>>(
          t0, x, nullptr, nullptr, 2048, 2048, 1,
          nullptr, nullptr, 0, 0, 0,
          Wp_h, Wp_l, 2048,
          nullptr, feC_h, feC_l, 2048, b_p, g_p, be_p);
      gmm<1, false><<<dim3(2 * Tp, 32), 256, 0, stream>>>(
          t0, nullptr, feC_h, feC_l, 2048, 2048, 0,
          sf_h, sf_l, 512, 512, 1,
          Wil_h, Wil_l, 2560,
          GxlC, nullptr, nullptr, 4096, bih_l, bhh_l, nullptr);
      gmm<1, false><<<dim3(2 * Tp, 16), 256, 0, stream>>>(
          t0, nullptr, sf_h, sf_l, 512, 512, 1,
          nullptr, nullptr, 0, 0, 0,
          Wis_h, Wis_l, 512,
          GxsC, nullptr, nullptr, 2048, bih_s, bhh_s, nullptr);

      for (int tt = 0; tt < Tp; ++tt) {
        const int t = t0 + tt;
        const int o = t & 1, nw = o ^ 1;
        step_g<<<dim3(2, 96), 256, 0, stream>>>(
            hl[o], hsb[o], Whl_h, Whl_l, Whs_h, Whs_l,
            GxlC + (long long)tt * 256 * 4096, GxsC + (long long)tt * 256 * 2048,
            gates_l, gates_s);
        step_upd<<<256, 256, 0, stream>>>(
            gates_l, gates_s, hl[o], cl[o], csb[o],
            hl[nw], cl[nw], hsb[nw], csb[nw],
            zs, W_g, b_g, r_out + (long long)t * 512, t);
      }
    }
    logits_k<<<256, 256, 0, stream>>>(hl[0], W_c, b_c, out);
    return;
  }

  // ---------------- all-f32 fallback (tiny workspace; R1 non-precomp) -------
  float* ws = (float*)d_ws;
  size_t offf = 0;
  auto allocf = [&](size_t n) { float* p = ws + offf; offf += n; return p; };
  float* feats   = allocf((size_t)BT * 2048);
  float* sfeats  = allocf((size_t)BT * 512);
  float* zs      = allocf((size_t)BT * 2);
  float* gates_l = allocf((size_t)256 * 4096);
  float* gates_s = allocf((size_t)256 * 2048);
  float* hl[2] = { allocf(256 * 1024), allocf(256 * 1024) };
  float* cl[2] = { allocf(256 * 1024), allocf(256 * 1024) };
  float* hsb[2] = { allocf(256 * 512),  allocf(256 * 512) };
  float* csb[2] = { allocf(256 * 512),  allocf(256 * 512) };

  hipMemsetAsync(hl[0], 0, 256 * 1024 * sizeof(float), stream);
  hipMemsetAsync(cl[0], 0, 256 * 1024 * sizeof(float), stream);
  hipMemsetAsync(hsb[0], 0, 256 * 512 * sizeof(float), stream);
  hipMemsetAsync(csb[0], 0, 256 * 512 * sizeof(float), stream);

  gemm_nt<128, 64, 8, 4, 0><<<dim3(BT / 128, 2048 / 64), 256, 0, stream>>>(
      BT, 2048, x, 2048, W_p, 2048, 2048,
      nullptr, 0, nullptr, 0, 0, nullptr, 0, nullptr, 0, 0,
      feats, 2048, b_p, g_p, be_p);
  gemm_nt<128, 64, 8, 4, 0><<<dim3(BT / 128, 512 / 64), 256, 0, stream>>>(
      BT, 512, xs, 1280, W_s, 1280, 1280,
      nullptr, 0, nullptr, 0, 0, nullptr, 0, nullptr, 0, 0,
      sfeats, 512, b_s, g_s, be_s);
  zs32_k<<<BT / 4, 256, 0, stream>>>(sfeats, W_g, zs);

  for (int t = 0; t < 64; ++t) {
    const int o = t & 1, nw = o ^ 1;
    gemm_nt<64, 64, 4, 4, 1><<<dim3(4, 2048 / 64), 256, 0, stream>>>(
        256, 2048, sfeats + (long long)t * 512, 64LL * 512, Wih_s, 512, 512,
        hsb[o], 512, Whh_s, 512, 512, nullptr, 0, nullptr, 0, 0,
        gates_s, 2048, bih_s, bhh_s, nullptr);
    gemm_nt<64, 64, 4, 4, 1><<<dim3(4, 4096 / 64), 256, 0, stream>>>(
        256, 4096, feats + (long long)t * 2048, 64LL * 2048, Wih_l, 2560, 2048,
        sfeats + (long long)t * 512, 64LL * 512, Wih_l + 2048, 2560, 512,
        hl[o], 1024, Whh_l, 1024, 1024,
        gates_l, 4096, bih_l, bhh_l, nullptr);
    step_upd<<<256, 256, 0, stream>>>(
        gates_l, gates_s, hl[o], cl[o], csb[o],
        hl[nw], cl[nw], hsb[nw], csb[nw],
        zs, W_g, b_g, r_out + (long long)t * 512, t);
  }
  logits_k<<<256, 256, 0, stream>>>(hl[0], W_c, b_c, out);
}

// Round 4
// 4990.980 us; speedup vs baseline: 3.2686x; 1.8785x over previous
//
#include <hip/hip_runtime.h>
#include <math.h>

// ---------------------------------------------------------------------------
// LiteEval gated dual-LSTM.  Round 4.
// All MFMA GEMM operands pre-packed into fragment-contiguous "images":
//   image elem (row = p*128 + j*16 + (lane&15), k = kt*32 + (lane>>4)*8 + e)
//   at f16 offset ((p*KT + kt)*8 + j)*512 + lane*8 + e          (KT = K/32)
// -> every global_load_lds(16B) instruction reads 1KB contiguous.
// 2-phase double-buffered K-loop (stage(next) -> compute(cur) -> barrier).
// f16 hi/lo split x3-MFMA (f32-grade accuracy) everywhere.
// Chunked time axis (Tp in {64..1}); fe/sf images produced tiled directly by
// the GEMM epilogue via an LDS bounce.  Fallback: all-f32 path.
// ---------------------------------------------------------------------------

typedef _Float16 f16;
typedef _Float16 f16x4 __attribute__((ext_vector_type(4)));
typedef _Float16 f16x8 __attribute__((ext_vector_type(8)));
typedef float f32x4 __attribute__((ext_vector_type(4)));

__device__ __forceinline__ float sigf(float x) { return 1.0f / (1.0f + expf(-x)); }

__device__ __forceinline__ void gload16(const f16* g, f16* l) {
  __builtin_amdgcn_global_load_lds((const __attribute__((address_space(1))) void*)g,
                                   (__attribute__((address_space(3))) void*)l, 16, 0, 0);
}

// ---------------------------------------------------------------------------
// pack f32 [R][C] row-major (optional chunk time-major row remap) -> image hi/lo
__global__ __launch_bounds__(256) void pack_img(const float* __restrict__ src,
    int C, int KT, int t0, int map, f16* __restrict__ dh, f16* __restrict__ dl,
    int slots)
{
  int gid = blockIdx.x * 256 + threadIdx.x;
  if (gid >= slots) return;
  int lane = gid & 63;
  int j = (gid >> 6) & 7;
  int pk = gid >> 9;
  int p = pk / KT, kt = pk - p * KT;
  int r = p * 128 + j * 16 + (lane & 15);
  int rg = map ? (((r & 255) << 6) + t0 + (r >> 8)) : r;
  int c = kt * 32 + (lane >> 4) * 8;
  const float* s = src + (long long)rg * C + c;
  float4 v0 = *(const float4*)s, v1 = *(const float4*)(s + 4);
  f16x8 h, l;
  h[0]=(f16)v0.x; l[0]=(f16)(v0.x-(float)h[0]);
  h[1]=(f16)v0.y; l[1]=(f16)(v0.y-(float)h[1]);
  h[2]=(f16)v0.z; l[2]=(f16)(v0.z-(float)h[2]);
  h[3]=(f16)v0.w; l[3]=(f16)(v0.w-(float)h[3]);
  h[4]=(f16)v1.x; l[4]=(f16)(v1.x-(float)h[4]);
  h[5]=(f16)v1.y; l[5]=(f16)(v1.y-(float)h[5]);
  h[6]=(f16)v1.z; l[6]=(f16)(v1.z-(float)h[6]);
  h[7]=(f16)v1.w; l[7]=(f16)(v1.w-(float)h[7]);
  *(f16x8*)(dh + (long long)gid * 8) = h;
  *(f16x8*)(dl + (long long)gid * 8) = l;
}

// pack both h-states each step (hl: 128 blocks, hs: 64 blocks)
__global__ __launch_bounds__(256) void pack_h2(const float* __restrict__ hl,
    const float* __restrict__ hs, f16* __restrict__ hlh, f16* __restrict__ hll,
    f16* __restrict__ hsh, f16* __restrict__ hsl)
{
  const float* src; f16 *dh, *dl; int C, KT, gid;
  if (blockIdx.x < 128) { src = hl; dh = hlh; dl = hll; C = 1024; KT = 32;
                          gid = blockIdx.x * 256 + threadIdx.x; }
  else                  { src = hs; dh = hsh; dl = hsl; C = 512;  KT = 16;
                          gid = (blockIdx.x - 128) * 256 + threadIdx.x; }
  int lane = gid & 63;
  int j = (gid >> 6) & 7;
  int pk = gid >> 9;
  int p = pk / KT, kt = pk - p * KT;
  int r = p * 128 + j * 16 + (lane & 15);
  int c = kt * 32 + (lane >> 4) * 8;
  const float* s = src + (long long)r * C + c;
  float4 v0 = *(const float4*)s, v1 = *(const float4*)(s + 4);
  f16x8 h, l;
  h[0]=(f16)v0.x; l[0]=(f16)(v0.x-(float)h[0]);
  h[1]=(f16)v0.y; l[1]=(f16)(v0.y-(float)h[1]);
  h[2]=(f16)v0.z; l[2]=(f16)(v0.z-(float)h[2]);
  h[3]=(f16)v0.w; l[3]=(f16)(v0.w-(float)h[3]);
  h[4]=(f16)v1.x; l[4]=(f16)(v1.x-(float)h[4]);
  h[5]=(f16)v1.y; l[5]=(f16)(v1.y-(float)h[5]);
  h[6]=(f16)v1.z; l[6]=(f16)(v1.z-(float)h[6]);
  h[7]=(f16)v1.w; l[7]=(f16)(v1.w-(float)h[7]);
  *(f16x8*)(dh + (long long)gid * 8) = h;
  *(f16x8*)(dl + (long long)gid * 8) = l;
}

// ---------------------------------------------------------------------------
// core split-MFMA GEMM on images.  128x128 tile, BK=32, 4 waves, 2-phase dbuf.
// EPI 0: relu((v+e0)*e1*s+e2) -> image hi/lo out (Ch,Cl, KTout) via LDS bounce
// EPI 1: v + e0[col]+e1[col] -> f32 row-major C (ldc)
// EPI 2: v + G[row*ldc+col]  -> f32 row-major C
template <int EPI>
__device__ __forceinline__ void gcore(int pA, int pB,
    const f16* __restrict__ Ah0, const f16* __restrict__ Al0, int KT0,
    const f16* __restrict__ Ah1, const f16* __restrict__ Al1, int KT1,
    const f16* __restrict__ Bh, const f16* __restrict__ Bl, int KTB,
    float* __restrict__ C, int ldc, const float* __restrict__ G,
    f16* __restrict__ Ch, f16* __restrict__ Cl, int KTout,
    const float* __restrict__ e0, const float* __restrict__ e1,
    const float* __restrict__ e2)
{
  __shared__ __align__(16) char smem[67584];   // 2x32KB dbuf | 128x132 f32 bounce
  f16 (*sm)[4][4096] = (f16 (*)[4][4096])smem;
  const int tid = threadIdx.x;
  const int w = tid >> 6, lane = tid & 63;
  const int wr = w >> 1, wc = w & 1;
  const int fr = lane & 15, fq = lane >> 4;

  const f16* aH0 = Ah0 + (long long)pA * KT0 * 4096;
  const f16* aL0 = Al0 + (long long)pA * KT0 * 4096;
  const f16* aH1 = Ah1 ? Ah1 + (long long)pA * KT1 * 4096 : nullptr;
  const f16* aL1 = Al1 ? Al1 + (long long)pA * KT1 * 4096 : nullptr;
  const f16* bH  = Bh + (long long)pB * KTB * 4096;
  const f16* bL  = Bl + (long long)pB * KTB * 4096;

  const int nt = KT0 + KT1;

  auto stage = [&](int buf, int kt) {
    const f16* src;
    if (w < 2) {
      if (kt < KT0) src = ((w == 0) ? aH0 : aL0) + (long long)kt * 4096;
      else          src = ((w == 0) ? aH1 : aL1) + (long long)(kt - KT0) * 4096;
    } else {
      src = ((w == 2) ? bH : bL) + (long long)kt * 4096;
    }
    f16* dst = &sm[buf][w][0];
#pragma unroll
    for (int j = 0; j < 8; ++j)
      gload16(src + j * 512 + lane * 8, dst + j * 512);
  };

  f32x4 acc[4][4];
#pragma unroll
  for (int m = 0; m < 4; ++m)
#pragma unroll
    for (int n = 0; n < 4; ++n) acc[m][n] = (f32x4){0.f, 0.f, 0.f, 0.f};

  stage(0, 0);
  __syncthreads();
  int cur = 0;
  for (int kt = 0; kt < nt; ++kt) {
    if (kt + 1 < nt) stage(cur ^ 1, kt + 1);   // prefetch next tile
    f16x8 bhx[4], blx[4];
#pragma unroll
    for (int n = 0; n < 4; ++n) {
      bhx[n] = *(const f16x8*)&sm[cur][2][(wc * 4 + n) * 512 + lane * 8];
      blx[n] = *(const f16x8*)&sm[cur][3][(wc * 4 + n) * 512 + lane * 8];
    }
#pragma unroll
    for (int m = 0; m < 4; ++m) {
      f16x8 ah = *(const f16x8*)&sm[cur][0][(wr * 4 + m) * 512 + lane * 8];
      f16x8 al = *(const f16x8*)&sm[cur][1][(wr * 4 + m) * 512 + lane * 8];
#pragma unroll
      for (int n = 0; n < 4; ++n) {
        acc[m][n] = __builtin_amdgcn_mfma_f32_16x16x32_f16(ah, bhx[n], acc[m][n], 0, 0, 0);
        acc[m][n] = __builtin_amdgcn_mfma_f32_16x16x32_f16(ah, blx[n], acc[m][n], 0, 0, 0);
        acc[m][n] = __builtin_amdgcn_mfma_f32_16x16x32_f16(al, bhx[n], acc[m][n], 0, 0, 0);
      }
    }
    __syncthreads();   // drains prefetch vmcnt; guards dbuf reuse
    cur ^= 1;
  }

  if (EPI == 1 || EPI == 2) {
    const int m0 = pA * 128, n0 = pB * 128;
#pragma unroll
    for (int m = 0; m < 4; ++m) {
#pragma unroll
      for (int n = 0; n < 4; ++n) {
        const int col = n0 + wc * 64 + n * 16 + fr;
        const float add = (EPI == 1) ? (e0[col] + e1[col]) : 0.f;
#pragma unroll
        for (int r = 0; r < 4; ++r) {
          const int row = m0 + wr * 64 + m * 16 + fq * 4 + r;
          float v = acc[m][n][r] + add;
          if (EPI == 2) v += G[(long long)row * ldc + col];
          C[(long long)row * ldc + col] = v;
        }
      }
    }
  } else {
    // BN+ReLU then tiled image output via f32 LDS bounce
    float* cb = (float*)smem;
    const int CBLD = 132;
#pragma unroll
    for (int m = 0; m < 4; ++m) {
#pragma unroll
      for (int n = 0; n < 4; ++n) {
        const int colL = wc * 64 + n * 16 + fr;
        const int colG = pB * 128 + colL;
        const float p0 = e0[colG], p1 = e1[colG] * 0.99999500003750f, p2 = e2[colG];
#pragma unroll
        for (int r = 0; r < 4; ++r) {
          const int rowL = wr * 64 + m * 16 + fq * 4 + r;
          cb[rowL * CBLD + colL] = fmaxf((acc[m][n][r] + p0) * p1 + p2, 0.f);
        }
      }
    }
    __syncthreads();
    const int ktL = tid >> 6;            // 0..3
    const int frO = lane & 15, fqO = lane >> 4;
#pragma unroll
    for (int j = 0; j < 8; ++j) {
      const int rowL = j * 16 + frO;
      const int kL = ktL * 32 + fqO * 8;
      const float* s = &cb[rowL * CBLD + kL];
      f16x8 h, l;
#pragma unroll
      for (int e = 0; e < 8; ++e) {
        float v = s[e];
        h[e] = (f16)v; l[e] = (f16)(v - (float)h[e]);
      }
      const long long o = (((long long)pA * KTout + (pB * 4 + ktL)) * 8 + j) * 512 + lane * 8;
      *(f16x8*)(Ch + o) = h;
      *(f16x8*)(Cl + o) = l;
    }
  }
}

template <int EPI>
__global__ __launch_bounds__(256) void gmmt(
    const f16* __restrict__ Ah0, const f16* __restrict__ Al0, int KT0,
    const f16* __restrict__ Ah1, const f16* __restrict__ Al1, int KT1,
    const f16* __restrict__ Bh, const f16* __restrict__ Bl, int KTB,
    float* __restrict__ C, int ldc, const float* __restrict__ G,
    f16* __restrict__ Ch, f16* __restrict__ Cl, int KTout,
    const float* __restrict__ e0, const float* __restrict__ e1,
    const float* __restrict__ e2)
{
  gcore<EPI>(blockIdx.x, blockIdx.y, Ah0, Al0, KT0, Ah1, Al1, KT1,
             Bh, Bl, KTB, C, ldc, G, Ch, Cl, KTout, e0, e1, e2);
}

// routed per-step recurrent GEMM: y<32 -> large (N=4096), y>=32 -> small (N=2048)
__global__ __launch_bounds__(256) void stepg_k(
    const f16* __restrict__ hlh, const f16* __restrict__ hll,
    const f16* __restrict__ hsh, const f16* __restrict__ hsl,
    const f16* __restrict__ Whl_h, const f16* __restrict__ Whl_l,
    const f16* __restrict__ Whs_h, const f16* __restrict__ Whs_l,
    const float* __restrict__ Gl, const float* __restrict__ Gs,
    float* __restrict__ gl, float* __restrict__ gs)
{
  if (blockIdx.y < 32)
    gcore<2>(blockIdx.x, blockIdx.y, hlh, hll, 32, nullptr, nullptr, 0,
             Whl_h, Whl_l, 32, gl, 4096, Gl, nullptr, nullptr, 0,
             nullptr, nullptr, nullptr);
  else
    gcore<2>(blockIdx.x, blockIdx.y - 32, hsh, hsl, 16, nullptr, nullptr, 0,
             Whs_h, Whs_l, 16, gs, 2048, Gs, nullptr, nullptr, 0,
             nullptr, nullptr, nullptr);
}

// zs from sf image (chunk): zs[bt,g] = sfeats[bt,:512] . W_g[g,:512]
__global__ __launch_bounds__(256) void zs_img_k(const f16* __restrict__ sfh,
    const f16* __restrict__ sfl, const float* __restrict__ Wg,
    float* __restrict__ zs, int t0)
{
  const int wv = threadIdx.x >> 6, lane = threadIdx.x & 63;
  const int rr = blockIdx.x * 4 + wv;
  const int p = rr >> 7, j = (rr >> 4) & 7, fr = rr & 15;
  const int kt = lane >> 2, fq = lane & 3;
  const long long a = (((long long)p * 16 + kt) * 8 + j) * 512 + (fq * 16 + fr) * 8;
  f16x8 h8 = *(const f16x8*)(sfh + a);
  f16x8 l8 = *(const f16x8*)(sfl + a);
  const int k0 = kt * 32 + fq * 8;
  float z0 = 0.f, z1 = 0.f;
#pragma unroll
  for (int i = 0; i < 8; ++i) {
    float s = (float)h8[i] + (float)l8[i];
    z0 += s * Wg[k0 + i]; z1 += s * Wg[2560 + k0 + i];
  }
#pragma unroll
  for (int off = 32; off > 0; off >>= 1) {
    z0 += __shfl_down(z0, off);
    z1 += __shfl_down(z1, off);
  }
  if (lane == 0) {
    const int bt = ((rr & 255) << 6) + t0 + (rr >> 8);
    zs[bt * 2] = z0; zs[bt * 2 + 1] = z1;
  }
}

// fused per-step update: gate argmax + small-cell update + large-cell blend
__global__ __launch_bounds__(256) void step_upd(
    const float* __restrict__ gl, const float* __restrict__ gs,
    const float* __restrict__ hl_o, const float* __restrict__ cl_o,
    const float* __restrict__ cs_o,
    float* __restrict__ hl_n, float* __restrict__ cl_n,
    float* __restrict__ hs_n, float* __restrict__ cs_n,
    const float* __restrict__ zs, const float* __restrict__ Wg,
    const float* __restrict__ bg, float* __restrict__ rout, int t)
{
  const int b = blockIdx.x, tid = threadIdx.x;
  __shared__ float red0[256], red1[256];
  __shared__ float shs[512], scs[512];
  __shared__ float rsh[2];

  float4 h4 = *(const float4*)(hl_o + (long long)b * 1024 + tid * 4);
  float4 c4 = *(const float4*)(cl_o + (long long)b * 1024 + tid * 4);
  float4 w0h = *(const float4*)(Wg + 512 + tid * 4);
  float4 w0c = *(const float4*)(Wg + 1536 + tid * 4);
  float4 w1h = *(const float4*)(Wg + 2560 + 512 + tid * 4);
  float4 w1c = *(const float4*)(Wg + 2560 + 1536 + tid * 4);
  red0[tid] = h4.x * w0h.x + h4.y * w0h.y + h4.z * w0h.z + h4.w * w0h.w
            + c4.x * w0c.x + c4.y * w0c.y + c4.z * w0c.z + c4.w * w0c.w;
  red1[tid] = h4.x * w1h.x + h4.y * w1h.y + h4.z * w1h.z + h4.w * w1h.w
            + c4.x * w1c.x + c4.y * w1c.y + c4.z * w1c.z + c4.w * w1c.w;

  {
    const float* gb = gs + (long long)b * 2048;
#pragma unroll
    for (int e = 0; e < 2; ++e) {
      const int n = tid * 2 + e;
      float gi = gb[n], gf = gb[512 + n], gg = gb[1024 + n], go = gb[1536 + n];
      float c2 = sigf(gf) * cs_o[b * 512 + n] + sigf(gi) * tanhf(gg);
      float h2 = sigf(go) * tanhf(c2);
      shs[n] = h2; scs[n] = c2;
      hs_n[b * 512 + n] = h2; cs_n[b * 512 + n] = c2;
    }
  }
  __syncthreads();
  for (int s = 128; s > 0; s >>= 1) {
    if (tid < s) { red0[tid] += red0[tid + s]; red1[tid] += red1[tid + s]; }
    __syncthreads();
  }
  if (tid == 0) {
    float z0 = red0[0] + zs[(b * 64 + t) * 2 + 0] + bg[0];
    float z1 = red1[0] + zs[(b * 64 + t) * 2 + 1] + bg[1];
    int hard = (z1 > z0) ? 1 : 0;   // jnp.argmax ties -> 0
    rsh[0] = hard ? 0.0f : 1.0f; rsh[1] = hard ? 1.0f : 0.0f;
    rout[b * 2 + 0] = rsh[0]; rout[b * 2 + 1] = rsh[1];
  }
  __syncthreads();
  const float r0 = rsh[0], r1 = rsh[1];

  {
    const float* glb = gl + (long long)b * 4096;
    const int n = tid * 4;
    float4 gi4 = *(const float4*)(glb + n);
    float4 gf4 = *(const float4*)(glb + 1024 + n);
    float4 gg4 = *(const float4*)(glb + 2048 + n);
    float4 go4 = *(const float4*)(glb + 3072 + n);
    float4 co4 = *(const float4*)(cl_o + (long long)b * 1024 + n);
    float4 ho4 = *(const float4*)(hl_o + (long long)b * 1024 + n);
    float gi[4] = {gi4.x, gi4.y, gi4.z, gi4.w};
    float gf[4] = {gf4.x, gf4.y, gf4.z, gf4.w};
    float gg[4] = {gg4.x, gg4.y, gg4.z, gg4.w};
    float go[4] = {go4.x, go4.y, go4.z, go4.w};
    float co[4] = {co4.x, co4.y, co4.z, co4.w};
    float ho[4] = {ho4.x, ho4.y, ho4.z, ho4.w};
    float hv[4], cv[4];
#pragma unroll
    for (int e = 0; e < 4; ++e) {
      float cln = sigf(gf[e]) * co[e] + sigf(gi[e]) * tanhf(gg[e]);
      float hln = sigf(go[e]) * tanhf(cln);
      float ph = (n + e < 512) ? shs[n + e] : ho[e];
      float pc = (n + e < 512) ? scs[n + e] : co[e];
      hv[e] = r0 * hln + r1 * ph;
      cv[e] = r0 * cln + r1 * pc;
    }
    float4 hw = {hv[0], hv[1], hv[2], hv[3]};
    float4 cw = {cv[0], cv[1], cv[2], cv[3]};
    *(float4*)(hl_n + (long long)b * 1024 + n) = hw;
    *(float4*)(cl_n + (long long)b * 1024 + n) = cw;
  }
}

// logits = h_l @ W_c^T + b_c
__global__ __launch_bounds__(256) void logits_k(const float* __restrict__ hl,
                                                const float* __restrict__ Wc,
                                                const float* __restrict__ bc,
                                                float* __restrict__ out)
{
  __shared__ float hsd[1024];
  const int b = blockIdx.x, tid = threadIdx.x;
  *(float4*)(hsd + tid * 4) = *(const float4*)(hl + (long long)b * 1024 + tid * 4);
  __syncthreads();
  if (tid < 239) {
    const float* w = Wc + (long long)tid * 1024;
    float s = 0.0f;
    for (int k = 0; k < 1024; k += 4) {
      float4 wv = *(const float4*)(w + k);
      s += hsd[k] * wv.x + hsd[k + 1] * wv.y + hsd[k + 2] * wv.z + hsd[k + 3] * wv.w;
    }
    out[(long long)b * 239 + tid] = s + bc[tid];
  }
}

// ===========================================================================
// all-f32 fallback (tiny workspace) — Round-1 proven path
#define BKK 32
template <int BM, int BN, int TM, int TN, int EPI>
__global__ __launch_bounds__(256) void gemm_nt(
    int M, int N,
    const float* __restrict__ A0, long long as0, const float* __restrict__ B0, long long bs0, int K0,
    const float* __restrict__ A1, long long as1, const float* __restrict__ B1, long long bs1, int K1,
    const float* __restrict__ A2, long long as2, const float* __restrict__ B2, long long bs2, int K2,
    float* __restrict__ C, long long ldc,
    const float* __restrict__ e0, const float* __restrict__ e1, const float* __restrict__ e2)
{
  __shared__ float As[BKK][BM + 4];
  __shared__ float Bs[BKK][BN + 4];
  const int tid = threadIdx.x;
  const int m0 = blockIdx.x * BM;
  const int n0 = blockIdx.y * BN;
  constexpr int C4 = BKK / 4;
  constexpr int RPP = 256 / C4;
  constexpr int APASS = BM / RPP;
  constexpr int BPASS = BN / RPP;
  const int lr = tid / C4;
  const int lc = tid % C4;
  float4 pa[APASS], pb[BPASS];
  const int nt = (K0 + K1 + K2) / BKK;
  auto load = [&](int kt) {
    const int kg = kt * BKK;
    const float* ap; long long as_; const float* bp; long long bs_;
    if (kg < K0)           { ap = A0 + kg;          as_ = as0; bp = B0 + kg;          bs_ = bs0; }
    else if (kg < K0 + K1) { int kl = kg - K0;      ap = A1 + kl; as_ = as1; bp = B1 + kl; bs_ = bs1; }
    else                   { int kl = kg - K0 - K1; ap = A2 + kl; as_ = as2; bp = B2 + kl; bs_ = bs2; }
#pragma unroll
    for (int p = 0; p < APASS; p++) {
      int r = lr + p * RPP;
      pa[p] = *(const float4*)(ap + (long long)(m0 + r) * as_ + lc * 4);
    }
#pragma unroll
    for (int p = 0; p < BPASS; p++) {
      int r = lr + p * RPP;
      pb[p] = *(const float4*)(bp + (long long)(n0 + r) * bs_ + lc * 4);
    }
  };
  const int tx = tid % (BN / TN);
  const int ty = tid / (BN / TN);
  float acc[TM][TN];
#pragma unroll
  for (int i = 0; i < TM; i++)
#pragma unroll
    for (int j = 0; j < TN; j++) acc[i][j] = 0.0f;
  load(0);
  for (int kt = 0; kt < nt; ++kt) {
    __syncthreads();
#pragma unroll
    for (int p = 0; p < APASS; p++) {
      int r = lr + p * RPP;
      As[lc * 4 + 0][r] = pa[p].x; As[lc * 4 + 1][r] = pa[p].y;
      As[lc * 4 + 2][r] = pa[p].z; As[lc * 4 + 3][r] = pa[p].w;
    }
#pragma unroll
    for (int p = 0; p < BPASS; p++) {
      int r = lr + p * RPP;
      Bs[lc * 4 + 0][r] = pb[p].x; Bs[lc * 4 + 1][r] = pb[p].y;
      Bs[lc * 4 + 2][r] = pb[p].z; Bs[lc * 4 + 3][r] = pb[p].w;
    }
    __syncthreads();
    if (kt + 1 < nt) load(kt + 1);
#pragma unroll
    for (int k = 0; k < BKK; k++) {
      float a[TM], b[TN];
#pragma unroll
      for (int i = 0; i < TM; i++) a[i] = As[k][ty * TM + i];
#pragma unroll
      for (int j = 0; j < TN; j++) b[j] = Bs[k][tx * TN + j];
#pragma unroll
      for (int i = 0; i < TM; i++)
#pragma unroll
        for (int j = 0; j < TN; j++) acc[i][j] += a[i] * b[j];
    }
  }
#pragma unroll
  for (int i = 0; i < TM; i++) {
    const int m = m0 + ty * TM + i;
    const int n = n0 + tx * TN;
    float v[TN];
#pragma unroll
    for (int j = 0; j < TN; j++) {
      float a = acc[i][j];
      if (EPI == 0) {
        float s = e1[n + j] * 0.999995f;
        a = (a + e0[n + j]) * s + e2[n + j];
        a = fmaxf(a, 0.0f);
      } else {
        a = a + e0[n + j] + e1[n + j];
      }
      v[j] = a;
    }
    float4 o; o.x = v[0]; o.y = v[1]; o.z = v[2]; o.w = v[3];
    *(float4*)(C + (long long)m * ldc + n) = o;
  }
}

__global__ __launch_bounds__(256) void zs32_k(const float* __restrict__ sf,
                                              const float* __restrict__ Wg,
                                              float* __restrict__ zs)
{
  const int wave = threadIdx.x >> 6, lane = threadIdx.x & 63;
  const int row = blockIdx.x * 4 + wave;
  const float* s = sf + (long long)row * 512 + lane * 8;
  const float* w0 = Wg + lane * 8;
  const float* w1 = Wg + 2560 + lane * 8;
  float4 sa = *(const float4*)s, sb = *(const float4*)(s + 4);
  float4 a0 = *(const float4*)w0, b0 = *(const float4*)(w0 + 4);
  float4 a1 = *(const float4*)w1, b1 = *(const float4*)(w1 + 4);
  float z0 = sa.x * a0.x + sa.y * a0.y + sa.z * a0.z + sa.w * a0.w
           + sb.x * b0.x + sb.y * b0.y + sb.z * b0.z + sb.w * b0.w;
  float z1 = sa.x * a1.x + sa.y * a1.y + sa.z * a1.z + sa.w * a1.w
           + sb.x * b1.x + sb.y * b1.y + sb.z * b1.z + sb.w * b1.w;
#pragma unroll
  for (int off = 32; off > 0; off >>= 1) {
    z0 += __shfl_down(z0, off);
    z1 += __shfl_down(z1, off);
  }
  if (lane == 0) { zs[row * 2] = z0; zs[row * 2 + 1] = z1; }
}

// ===========================================================================
extern "C" void kernel_launch(void* const* d_in, const int* in_sizes, int n_in,
                              void* d_out, int out_size, void* d_ws, size_t ws_size,
                              hipStream_t stream)
{
  const float* x     = (const float*)d_in[0];
  const float* xs    = (const float*)d_in[1];
  const float* W_p   = (const float*)d_in[2];
  const float* b_p   = (const float*)d_in[3];
  const float* g_p   = (const float*)d_in[4];
  const float* be_p  = (const float*)d_in[5];
  const float* W_s   = (const float*)d_in[6];
  const float* b_s   = (const float*)d_in[7];
  const float* g_s   = (const float*)d_in[8];
  const float* be_s  = (const float*)d_in[9];
  const float* Wih_l = (const float*)d_in[10];
  const float* Whh_l = (const float*)d_in[11];
  const float* bih_l = (const float*)d_in[12];
  const float* bhh_l = (const float*)d_in[13];
  const float* Wih_s = (const float*)d_in[14];
  const float* Whh_s = (const float*)d_in[15];
  const float* bih_s = (const float*)d_in[16];
  const float* bhh_s = (const float*)d_in[17];
  const float* W_g   = (const float*)d_in[18];
  const float* b_g   = (const float*)d_in[19];
  const float* W_c   = (const float*)d_in[20];
  const float* b_c   = (const float*)d_in[21];
  float* out = (float*)d_out;
  float* r_out = out + 61184;            // [64][256][2]

  const int BT = 16384;
  const size_t FIXEDB = 100794368ULL;
  const size_t CHUNKB = 12320768ULL;
  int Tp = 0;
  for (int T = 64; T >= 1; T >>= 1)
    if (FIXEDB + CHUNKB * (size_t)T + 65536 <= ws_size) { Tp = T; break; }

  if (Tp > 0) {
    char* base = (char*)d_ws;
    size_t off = 0;
    auto alloc = [&](size_t n) { void* p = base + off; off += (n + 255) & ~255ULL; return p; };
    // weight images (hi/lo)
    f16* WpI[2]  = {(f16*)alloc(8388608),  (f16*)alloc(8388608)};
    f16* WsI[2]  = {(f16*)alloc(1310720),  (f16*)alloc(1310720)};
    f16* WilI[2] = {(f16*)alloc(20971520), (f16*)alloc(20971520)};
    f16* WisI[2] = {(f16*)alloc(2097152),  (f16*)alloc(2097152)};
    f16* WhlI[2] = {(f16*)alloc(8388608),  (f16*)alloc(8388608)};
    f16* WhsI[2] = {(f16*)alloc(2097152),  (f16*)alloc(2097152)};
    // per-step h images
    f16* hlI[2] = {(f16*)alloc(524288), (f16*)alloc(524288)};
    f16* hsI[2] = {(f16*)alloc(262144), (f16*)alloc(262144)};
    float* zs  = (float*)alloc(131072);
    float* hl[2] = {(float*)alloc(1048576), (float*)alloc(1048576)};
    float* cl[2] = {(float*)alloc(1048576), (float*)alloc(1048576)};
    float* hsb[2] = {(float*)alloc(524288), (float*)alloc(524288)};
    float* csb[2] = {(float*)alloc(524288), (float*)alloc(524288)};
    float* gates_l = (float*)alloc(4194304);
    float* gates_s = (float*)alloc(2097152);
    // chunk buffers
    f16* xI[2]  = {(f16*)alloc(1048576ULL * Tp), (f16*)alloc(1048576ULL * Tp)};
    f16* xsI[2] = {(f16*)alloc(655360ULL * Tp),  (f16*)alloc(655360ULL * Tp)};
    f16* feI[2] = {(f16*)alloc(1048576ULL * Tp), (f16*)alloc(1048576ULL * Tp)};
    f16* sfI[2] = {(f16*)alloc(262144ULL * Tp),  (f16*)alloc(262144ULL * Tp)};
    float* GxlC = (float*)alloc(4194304ULL * Tp);
    float* GxsC = (float*)alloc(2097152ULL * Tp);

    // one-time weight packs
    pack_img<<<2048, 256, 0, stream>>>(W_p,   2048, 64, 0, 0, WpI[0],  WpI[1],  524288);
    pack_img<<<320,  256, 0, stream>>>(W_s,   1280, 40, 0, 0, WsI[0],  WsI[1],  81920);
    pack_img<<<5120, 256, 0, stream>>>(Wih_l, 2560, 80, 0, 0, WilI[0], WilI[1], 1310720);
    pack_img<<<512,  256, 0, stream>>>(Wih_s, 512,  16, 0, 0, WisI[0], WisI[1], 131072);
    pack_img<<<2048, 256, 0, stream>>>(Whh_l, 1024, 32, 0, 0, WhlI[0], WhlI[1], 524288);
    pack_img<<<512,  256, 0, stream>>>(Whh_s, 512,  16, 0, 0, WhsI[0], WhsI[1], 131072);

    hipMemsetAsync(hl[0], 0, 1048576, stream);
    hipMemsetAsync(cl[0], 0, 1048576, stream);
    hipMemsetAsync(hsb[0], 0, 524288, stream);
    hipMemsetAsync(csb[0], 0, 524288, stream);

    const int rows = 256 * Tp;             // chunk rows (time-major)
    for (int t0 = 0; t0 < 64; t0 += Tp) {
      // pack input chunks (time-major remap absorbed here)
      pack_img<<<rows * 2048 / 8 / 256, 256, 0, stream>>>(
          x, 2048, 64, t0, 1, xI[0], xI[1], rows * 256);
      pack_img<<<rows * 1280 / 8 / 256, 256, 0, stream>>>(
          xs, 1280, 40, t0, 1, xsI[0], xsI[1], rows * 160);
      // sfeats chunk -> sf image
      gmmt<0><<<dim3(rows / 128, 4), 256, 0, stream>>>(
          xsI[0], xsI[1], 40, nullptr, nullptr, 0,
          WsI[0], WsI[1], 40,
          nullptr, 0, nullptr, sfI[0], sfI[1], 16, b_s, g_s, be_s);
      zs_img_k<<<rows / 4, 256, 0, stream>>>(sfI[0], sfI[1], W_g, zs, t0);
      // feats chunk -> fe image
      gmmt<0><<<dim3(rows / 128, 16), 256, 0, stream>>>(
          xI[0], xI[1], 64, nullptr, nullptr, 0,
          WpI[0], WpI[1], 64,
          nullptr, 0, nullptr, feI[0], feI[1], 64, b_p, g_p, be_p);
      // Gx_l = [fe|sf] @ Wih_l^T + bih_l + bhh_l
      gmmt<1><<<dim3(rows / 128, 32), 256, 0, stream>>>(
          feI[0], feI[1], 64, sfI[0], sfI[1], 16,
          WilI[0], WilI[1], 80,
          GxlC, 4096, nullptr, nullptr, nullptr, 0, bih_l, bhh_l, nullptr);
      // Gx_s = sf @ Wih_s^T + bih_s + bhh_s
      gmmt<1><<<dim3(rows / 128, 16), 256, 0, stream>>>(
          sfI[0], sfI[1], 16, nullptr, nullptr, 0,
          WisI[0], WisI[1], 16,
          GxsC, 2048, nullptr, nullptr, nullptr, 0, bih_s, bhh_s, nullptr);

      for (int tt = 0; tt < Tp; ++tt) {
        const int t = t0 + tt;
        const int o = t & 1, nw = o ^ 1;
        pack_h2<<<192, 256, 0, stream>>>(hl[o], hsb[o],
                                         hlI[0], hlI[1], hsI[0], hsI[1]);
        stepg_k<<<dim3(2, 48), 256, 0, stream>>>(
            hlI[0], hlI[1], hsI[0], hsI[1],
            WhlI[0], WhlI[1], WhsI[0], WhsI[1],
            GxlC + (long long)tt * 256 * 4096, GxsC + (long long)tt * 256 * 2048,
            gates_l, gates_s);
        step_upd<<<256, 256, 0, stream>>>(
            gates_l, gates_s, hl[o], cl[o], csb[o],
            hl[nw], cl[nw], hsb[nw], csb[nw],
            zs, W_g, b_g, r_out + (long long)t * 512, t);
      }
    }
    logits_k<<<256, 256, 0, stream>>>(hl[0], W_c, b_c, out);
    return;
  }

  // ---------------- all-f32 fallback (tiny workspace) ----------------
  float* ws = (float*)d_ws;
  size_t offf = 0;
  auto allocf = [&](size_t n) { float* p = ws + offf; offf += n; return p; };
  float* feats   = allocf((size_t)BT * 2048);
  float* sfeats  = allocf((size_t)BT * 512);
  float* zs      = allocf((size_t)BT * 2);
  float* gates_l = allocf((size_t)256 * 4096);
  float* gates_s = allocf((size_t)256 * 2048);
  float* hl[2] = { allocf(256 * 1024), allocf(256 * 1024) };
  float* cl[2] = { allocf(256 * 1024), allocf(256 * 1024) };
  float* hsb[2] = { allocf(256 * 512),  allocf(256 * 512) };
  float* csb[2] = { allocf(256 * 512),  allocf(256 * 512) };

  hipMemsetAsync(hl[0], 0, 256 * 1024 * sizeof(float), stream);
  hipMemsetAsync(cl[0], 0, 256 * 1024 * sizeof(float), stream);
  hipMemsetAsync(hsb[0], 0, 256 * 512 * sizeof(float), stream);
  hipMemsetAsync(csb[0], 0, 256 * 512 * sizeof(float), stream);

  gemm_nt<128, 64, 8, 4, 0><<<dim3(BT / 128, 2048 / 64), 256, 0, stream>>>(
      BT, 2048, x, 2048, W_p, 2048, 2048,
      nullptr, 0, nullptr, 0, 0, nullptr, 0, nullptr, 0, 0,
      feats, 2048, b_p, g_p, be_p);
  gemm_nt<128, 64, 8, 4, 0><<<dim3(BT / 128, 512 / 64), 256, 0, stream>>>(
      BT, 512, xs, 1280, W_s, 1280, 1280,
      nullptr, 0, nullptr, 0, 0, nullptr, 0, nullptr, 0, 0,
      sfeats, 512, b_s, g_s, be_s);
  zs32_k<<<BT / 4, 256, 0, stream>>>(sfeats, W_g, zs);

  for (int t = 0; t < 64; ++t) {
    const int o = t & 1, nw = o ^ 1;
    gemm_nt<64, 64, 4, 4, 1><<<dim3(4, 2048 / 64), 256, 0, stream>>>(
        256, 2048, sfeats + (long long)t * 512, 64LL * 512, Wih_s, 512, 512,
        hsb[o], 512, Whh_s, 512, 512, nullptr, 0, nullptr, 0, 0,
        gates_s, 2048, bih_s, bhh_s, nullptr);
    gemm_nt<64, 64, 4, 4, 1><<<dim3(4, 4096 / 64), 256, 0, stream>>>(
        256, 4096, feats + (long long)t * 2048, 64LL * 2048, Wih_l, 2560, 2048,
        sfeats + (long long)t * 512, 64LL * 512, Wih_l + 2048, 2560, 512,
        hl[o], 1024, Whh_l, 1024, 1024,
        gates_l, 4096, bih_l, bhh_l, nullptr);
    step_upd<<<256, 256, 0, stream>>>(
        gates_l, gates_s, hl[o], cl[o], csb[o],
        hl[nw], cl[nw], hsb[nw], csb[nw],
        zs, W_g, b_g, r_out + (long long)t * 512, t);
  }
  logits_k<<<256, 256, 0, stream>>>(hl[0], W_c, b_c, out);
}

// Round 5
// 3934.571 us; speedup vs baseline: 4.1462x; 1.2685x over previous
//
#include <hip/hip_runtime.h>
#include <math.h>

// ---------------------------------------------------------------------------
// LiteEval gated dual-LSTM.  Round 5.
//  * Big per-chunk GEMMs -> 256x256-tile 8-wave (512 thr) split-f16 MFMA,
//    2-phase double-buffer (T3 minimum recipe), fragment-linear LDS (128 KB),
//    96 MFMA/wave per K=32 step.  Halves operand re-reads vs 128x128 and
//    amortizes the barrier drain over 4x more MFMA.
//  * Images (fragment-contiguous operand layouts) unchanged from R4: every
//    global_load_lds(16B) reads 1KB contiguous.
//  * pack_h2 fused into step_upd (h-state images written in the update).
//  * Sequential stepg keeps the proven 128x128 gcore.
//  * Fallback: all-f32 path for tiny workspace.
// ---------------------------------------------------------------------------

typedef _Float16 f16;
typedef _Float16 f16x4 __attribute__((ext_vector_type(4)));
typedef _Float16 f16x8 __attribute__((ext_vector_type(8)));
typedef float f32x4 __attribute__((ext_vector_type(4)));

__device__ __forceinline__ float sigf(float x) { return 1.0f / (1.0f + expf(-x)); }

__device__ __forceinline__ void gload16(const f16* g, f16* l) {
  __builtin_amdgcn_global_load_lds((const __attribute__((address_space(1))) void*)g,
                                   (__attribute__((address_space(3))) void*)l, 16, 0, 0);
}

// ---------------------------------------------------------------------------
// pack f32 [R][C] row-major (optional chunk time-major row remap) -> image hi/lo
// image elem (row = p*128 + j*16 + (lane&15), k = kt*32 + (lane>>4)*8 + e)
// at f16 offset ((p*KT + kt)*8 + j)*512 + lane*8 + e           (KT = K/32)
__global__ __launch_bounds__(256) void pack_img(const float* __restrict__ src,
    int C, int KT, int t0, int map, f16* __restrict__ dh, f16* __restrict__ dl,
    int slots)
{
  int gid = blockIdx.x * 256 + threadIdx.x;
  if (gid >= slots) return;
  int lane = gid & 63;
  int j = (gid >> 6) & 7;
  int pk = gid >> 9;
  int p = pk / KT, kt = pk - p * KT;
  int r = p * 128 + j * 16 + (lane & 15);
  int rg = map ? (((r & 255) << 6) + t0 + (r >> 8)) : r;
  int c = kt * 32 + (lane >> 4) * 8;
  const float* s = src + (long long)rg * C + c;
  float4 v0 = *(const float4*)s, v1 = *(const float4*)(s + 4);
  f16x8 h, l;
  h[0]=(f16)v0.x; l[0]=(f16)(v0.x-(float)h[0]);
  h[1]=(f16)v0.y; l[1]=(f16)(v0.y-(float)h[1]);
  h[2]=(f16)v0.z; l[2]=(f16)(v0.z-(float)h[2]);
  h[3]=(f16)v0.w; l[3]=(f16)(v0.w-(float)h[3]);
  h[4]=(f16)v1.x; l[4]=(f16)(v1.x-(float)h[4]);
  h[5]=(f16)v1.y; l[5]=(f16)(v1.y-(float)h[5]);
  h[6]=(f16)v1.z; l[6]=(f16)(v1.z-(float)h[6]);
  h[7]=(f16)v1.w; l[7]=(f16)(v1.w-(float)h[7]);
  *(f16x8*)(dh + (long long)gid * 8) = h;
  *(f16x8*)(dl + (long long)gid * 8) = l;
}

// ---------------------------------------------------------------------------
// 256x256-tile split-f16 MFMA GEMM on images. 512 threads = 8 waves (2M x 4N).
// BK=32; LDS: 2 x {Ah,Al,Bh,Bl} x 16KB = 128 KB; 2-phase double buffer.
// A: up to 2 K-segments of images; B: one image.  nt = KT0+KT1 (= KTB).
// EPI 0: relu((v+e0)*e1*s+e2) -> image hi/lo out (Ch,Cl,KTout) via LDS bounce
// EPI 1: v + e0[col] + e1[col] -> f32 row-major C (ldc)
template <int EPI>
__global__ __launch_bounds__(512, 1) void gmm256(
    const f16* __restrict__ Ah0, const f16* __restrict__ Al0, int KT0,
    const f16* __restrict__ Ah1, const f16* __restrict__ Al1, int KT1,
    const f16* __restrict__ Bh, const f16* __restrict__ Bl, int KTB,
    float* __restrict__ C, int ldc,
    f16* __restrict__ Ch, f16* __restrict__ Cl, int KTout,
    const float* __restrict__ e0, const float* __restrict__ e1,
    const float* __restrict__ e2)
{
  __shared__ __align__(16) char smem[131072];
  f16 (*sm)[4][8192] = (f16 (*)[4][8192])smem;   // [buf][Ah,Al,Bh,Bl][...]
  const int tid = threadIdx.x;
  const int w = tid >> 6, lane = tid & 63;
  const int wr = w >> 2, wc = w & 3;             // 2 M-waves x 4 N-waves
  const int fr = lane & 15, fq = lane >> 4;
  const int pA = blockIdx.y, pB = blockIdx.x;
  const int sarr = w >> 1, shalf = w & 1;        // staging: array, panel half

  const int nt = KT0 + KT1;

  auto stage = [&](int buf, int kt) {
    const f16* base;
    if (sarr >= 2) {
      base = ((sarr == 2) ? Bh : Bl) + ((long long)(pB * 2 + shalf) * KTB + kt) * 4096;
    } else if (kt < KT0) {
      base = ((sarr == 0) ? Ah0 : Al0) + ((long long)(pA * 2 + shalf) * KT0 + kt) * 4096;
    } else {
      base = ((sarr == 0) ? Ah1 : Al1) + ((long long)(pA * 2 + shalf) * KT1 + (kt - KT0)) * 4096;
    }
    f16* dst = &sm[buf][sarr][shalf * 4096];
#pragma unroll
    for (int j = 0; j < 8; ++j)
      gload16(base + j * 512 + lane * 8, dst + j * 512);
  };

  f32x4 acc[8][4];
#pragma unroll
  for (int m = 0; m < 8; ++m)
#pragma unroll
    for (int n = 0; n < 4; ++n) acc[m][n] = (f32x4){0.f, 0.f, 0.f, 0.f};

  stage(0, 0);
  __syncthreads();
  int cur = 0;
  for (int kt = 0; kt < nt; ++kt) {
    if (kt + 1 < nt) stage(cur ^ 1, kt + 1);     // prefetch next K-tile
    f16x8 bh_[4], bl_[4];
#pragma unroll
    for (int n = 0; n < 4; ++n) {
      bh_[n] = *(const f16x8*)&sm[cur][2][(wc * 4 + n) * 512 + lane * 8];
      bl_[n] = *(const f16x8*)&sm[cur][3][(wc * 4 + n) * 512 + lane * 8];
    }
#pragma unroll
    for (int m = 0; m < 8; ++m) {
      f16x8 ah = *(const f16x8*)&sm[cur][0][wr * 4096 + m * 512 + lane * 8];
      f16x8 al = *(const f16x8*)&sm[cur][1][wr * 4096 + m * 512 + lane * 8];
#pragma unroll
      for (int n = 0; n < 4; ++n) {
        acc[m][n] = __builtin_amdgcn_mfma_f32_16x16x32_f16(ah, bh_[n], acc[m][n], 0, 0, 0);
        acc[m][n] = __builtin_amdgcn_mfma_f32_16x16x32_f16(ah, bl_[n], acc[m][n], 0, 0, 0);
        acc[m][n] = __builtin_amdgcn_mfma_f32_16x16x32_f16(al, bh_[n], acc[m][n], 0, 0, 0);
      }
    }
    __syncthreads();                             // drains prefetch; guards dbuf
    cur ^= 1;
  }

  if (EPI == 1) {
#pragma unroll
    for (int m = 0; m < 8; ++m) {
#pragma unroll
      for (int n = 0; n < 4; ++n) {
        const int col = pB * 256 + wc * 64 + n * 16 + fr;
        const float add = e0[col] + e1[col];
#pragma unroll
        for (int r = 0; r < 4; ++r) {
          const int row = pA * 256 + wr * 128 + m * 16 + fq * 4 + r;
          C[(long long)row * ldc + col] = acc[m][n][r] + add;
        }
      }
    }
  } else {
    // BN+ReLU -> image out via quarter-tile (64-row) f32 LDS bounce
    float* cb = (float*)smem;
    const int CBLD = 260;
    for (int q = 0; q < 4; ++q) {
      __syncthreads();
      if (wr == (q >> 1)) {
#pragma unroll
        for (int mm = 0; mm < 4; ++mm) {
          const int m = (q & 1) * 4 + mm;
#pragma unroll
          for (int n = 0; n < 4; ++n) {
            const int colL = wc * 64 + n * 16 + fr;
            const int colG = pB * 256 + colL;
            const float p0 = e0[colG], p1 = e1[colG] * 0.99999500003750f, p2 = e2[colG];
#pragma unroll
            for (int r = 0; r < 4; ++r) {
              const int rq = mm * 16 + fq * 4 + r;
              cb[rq * CBLD + colL] = fmaxf((acc[m][n][r] + p0) * p1 + p2, 0.f);
            }
          }
        }
      }
      __syncthreads();
      // readout: wave w handles k-tile ktl=w; lanes: fr_o row, fq_o k-sub
      const int ktl = w;
      const int p_out = pA * 2 + (q >> 1);
#pragma unroll
      for (int jp = 0; jp < 4; ++jp) {
        const int rL = jp * 16 + fr;
        const float* s = &cb[rL * CBLD + ktl * 32 + fq * 8];
        float4 v0 = *(const float4*)s, v1 = *(const float4*)(s + 4);
        float vv[8] = {v0.x, v0.y, v0.z, v0.w, v1.x, v1.y, v1.z, v1.w};
        f16x8 h, l;
#pragma unroll
        for (int e = 0; e < 8; ++e) {
          h[e] = (f16)vv[e]; l[e] = (f16)(vv[e] - (float)h[e]);
        }
        const int j_img = (q & 1) * 4 + jp;
        const long long o =
            (((long long)p_out * KTout + (pB * 8 + ktl)) * 8 + j_img) * 512 + lane * 8;
        *(f16x8*)(Ch + o) = h;
        *(f16x8*)(Cl + o) = l;
      }
    }
  }
}

// ---------------------------------------------------------------------------
// 128x128-tile split-MFMA gcore (EPI 2: v + G) — used for per-step recurrent
// GEMM only (M=256, operands L2/L3-resident).  Proven in R4.
__device__ __forceinline__ void gcore_step(int pA, int pB,
    const f16* __restrict__ Ah0, const f16* __restrict__ Al0, int KT0,
    const f16* __restrict__ Bh, const f16* __restrict__ Bl,
    float* __restrict__ C, int ldc, const float* __restrict__ G)
{
  __shared__ __align__(16) char smem[65536];
  f16 (*sm)[4][4096] = (f16 (*)[4][4096])smem;
  const int tid = threadIdx.x;
  const int w = tid >> 6, lane = tid & 63;
  const int wr = w >> 1, wc = w & 1;
  const int fr = lane & 15, fq = lane >> 4;

  const f16* aH = Ah0 + (long long)pA * KT0 * 4096;
  const f16* aL = Al0 + (long long)pA * KT0 * 4096;
  const f16* bH = Bh + (long long)pB * KT0 * 4096;
  const f16* bL = Bl + (long long)pB * KT0 * 4096;

  auto stage = [&](int buf, int kt) {
    const f16* src;
    if (w == 0)      src = aH + (long long)kt * 4096;
    else if (w == 1) src = aL + (long long)kt * 4096;
    else if (w == 2) src = bH + (long long)kt * 4096;
    else             src = bL + (long long)kt * 4096;
    f16* dst = &sm[buf][w][0];
#pragma unroll
    for (int j = 0; j < 8; ++j)
      gload16(src + j * 512 + lane * 8, dst + j * 512);
  };

  f32x4 acc[4][4];
#pragma unroll
  for (int m = 0; m < 4; ++m)
#pragma unroll
    for (int n = 0; n < 4; ++n) acc[m][n] = (f32x4){0.f, 0.f, 0.f, 0.f};

  stage(0, 0);
  __syncthreads();
  int cur = 0;
  for (int kt = 0; kt < KT0; ++kt) {
    if (kt + 1 < KT0) stage(cur ^ 1, kt + 1);
    f16x8 bhx[4], blx[4];
#pragma unroll
    for (int n = 0; n < 4; ++n) {
      bhx[n] = *(const f16x8*)&sm[cur][2][(wc * 4 + n) * 512 + lane * 8];
      blx[n] = *(const f16x8*)&sm[cur][3][(wc * 4 + n) * 512 + lane * 8];
    }
#pragma unroll
    for (int m = 0; m < 4; ++m) {
      f16x8 ah = *(const f16x8*)&sm[cur][0][(wr * 4 + m) * 512 + lane * 8];
      f16x8 al = *(const f16x8*)&sm[cur][1][(wr * 4 + m) * 512 + lane * 8];
#pragma unroll
      for (int n = 0; n < 4; ++n) {
        acc[m][n] = __builtin_amdgcn_mfma_f32_16x16x32_f16(ah, bhx[n], acc[m][n], 0, 0, 0);
        acc[m][n] = __builtin_amdgcn_mfma_f32_16x16x32_f16(ah, blx[n], acc[m][n], 0, 0, 0);
        acc[m][n] = __builtin_amdgcn_mfma_f32_16x16x32_f16(al, bhx[n], acc[m][n], 0, 0, 0);
      }
    }
    __syncthreads();
    cur ^= 1;
  }

#pragma unroll
  for (int m = 0; m < 4; ++m) {
#pragma unroll
    for (int n = 0; n < 4; ++n) {
      const int col = pB * 128 + wc * 64 + n * 16 + fr;
#pragma unroll
      for (int r = 0; r < 4; ++r) {
        const int row = pA * 128 + wr * 64 + m * 16 + fq * 4 + r;
        const long long idx = (long long)row * ldc + col;
        C[idx] = acc[m][n][r] + G[idx];
      }
    }
  }
}

// routed per-step recurrent GEMM: y<32 -> large (N=4096,K=1024), else small
__global__ __launch_bounds__(256) void stepg_k(
    const f16* __restrict__ hlh, const f16* __restrict__ hll,
    const f16* __restrict__ hsh, const f16* __restrict__ hsl,
    const f16* __restrict__ Whl_h, const f16* __restrict__ Whl_l,
    const f16* __restrict__ Whs_h, const f16* __restrict__ Whs_l,
    const float* __restrict__ Gl, const float* __restrict__ Gs,
    float* __restrict__ gl, float* __restrict__ gs)
{
  if (blockIdx.y < 32)
    gcore_step(blockIdx.x, blockIdx.y, hlh, hll, 32,
               Whl_h, Whl_l, gl, 4096, Gl);
  else
    gcore_step(blockIdx.x, blockIdx.y - 32, hsh, hsl, 16,
               Whs_h, Whs_l, gs, 2048, Gs);
}

// zs from sf image (chunk): zs[bt,g] = sfeats[bt,:512] . W_g[g,:512]
__global__ __launch_bounds__(256) void zs_img_k(const f16* __restrict__ sfh,
    const f16* __restrict__ sfl, const float* __restrict__ Wg,
    float* __restrict__ zs, int t0)
{
  const int wv = threadIdx.x >> 6, lane = threadIdx.x & 63;
  const int rr = blockIdx.x * 4 + wv;
  const int p = rr >> 7, j = (rr >> 4) & 7, fr = rr & 15;
  const int kt = lane >> 2, fq = lane & 3;
  const long long a = (((long long)p * 16 + kt) * 8 + j) * 512 + (fq * 16 + fr) * 8;
  f16x8 h8 = *(const f16x8*)(sfh + a);
  f16x8 l8 = *(const f16x8*)(sfl + a);
  const int k0 = kt * 32 + fq * 8;
  float z0 = 0.f, z1 = 0.f;
#pragma unroll
  for (int i = 0; i < 8; ++i) {
    float s = (float)h8[i] + (float)l8[i];
    z0 += s * Wg[k0 + i]; z1 += s * Wg[2560 + k0 + i];
  }
#pragma unroll
  for (int off = 32; off > 0; off >>= 1) {
    z0 += __shfl_down(z0, off);
    z1 += __shfl_down(z1, off);
  }
  if (lane == 0) {
    const int bt = ((rr & 255) << 6) + t0 + (rr >> 8);
    zs[bt * 2] = z0; zs[bt * 2 + 1] = z1;
  }
}

// fused per-step update: gate argmax + small-cell + large-cell blend + write
// the NEW h-state images (pack_h2 fused in).
__global__ __launch_bounds__(256) void step_upd(
    const float* __restrict__ gl, const float* __restrict__ gs,
    const float* __restrict__ hl_o, const float* __restrict__ cl_o,
    const float* __restrict__ cs_o,
    float* __restrict__ hl_n, float* __restrict__ cl_n,
    float* __restrict__ hs_n, float* __restrict__ cs_n,
    f16* __restrict__ hlIh, f16* __restrict__ hlIl,
    f16* __restrict__ hsIh, f16* __restrict__ hsIl,
    const float* __restrict__ zs, const float* __restrict__ Wg,
    const float* __restrict__ bg, float* __restrict__ rout, int t)
{
  const int b = blockIdx.x, tid = threadIdx.x;
  __shared__ float red0[256], red1[256];
  __shared__ float shs[512], scs[512];
  __shared__ float rsh[2];

  const int pb = b >> 7, jb = (b >> 4) & 7, frb = b & 15;

  float4 h4 = *(const float4*)(hl_o + (long long)b * 1024 + tid * 4);
  float4 c4 = *(const float4*)(cl_o + (long long)b * 1024 + tid * 4);
  float4 w0h = *(const float4*)(Wg + 512 + tid * 4);
  float4 w0c = *(const float4*)(Wg + 1536 + tid * 4);
  float4 w1h = *(const float4*)(Wg + 2560 + 512 + tid * 4);
  float4 w1c = *(const float4*)(Wg + 2560 + 1536 + tid * 4);
  red0[tid] = h4.x * w0h.x + h4.y * w0h.y + h4.z * w0h.z + h4.w * w0h.w
            + c4.x * w0c.x + c4.y * w0c.y + c4.z * w0c.z + c4.w * w0c.w;
  red1[tid] = h4.x * w1h.x + h4.y * w1h.y + h4.z * w1h.z + h4.w * w1h.w
            + c4.x * w1c.x + c4.y * w1c.y + c4.z * w1c.z + c4.w * w1c.w;

  {
    const float* gb = gs + (long long)b * 2048;
#pragma unroll
    for (int e = 0; e < 2; ++e) {
      const int n = tid * 2 + e;
      float gi = gb[n], gf = gb[512 + n], gg = gb[1024 + n], go = gb[1536 + n];
      float c2 = sigf(gf) * cs_o[b * 512 + n] + sigf(gi) * tanhf(gg);
      float h2 = sigf(go) * tanhf(c2);
      shs[n] = h2; scs[n] = c2;
      hs_n[b * 512 + n] = h2; cs_n[b * 512 + n] = c2;
      // hs image (KT=16)
      const int kt = n >> 5, fqn = (n >> 3) & 3, en = n & 7;
      const long long o = (((long long)pb * 16 + kt) * 8 + jb) * 512
                        + (fqn * 16 + frb) * 8 + en;
      f16 hh = (f16)h2;
      hsIh[o] = hh; hsIl[o] = (f16)(h2 - (float)hh);
    }
  }
  __syncthreads();
  for (int s = 128; s > 0; s >>= 1) {
    if (tid < s) { red0[tid] += red0[tid + s]; red1[tid] += red1[tid + s]; }
    __syncthreads();
  }
  if (tid == 0) {
    float z0 = red0[0] + zs[(b * 64 + t) * 2 + 0] + bg[0];
    float z1 = red1[0] + zs[(b * 64 + t) * 2 + 1] + bg[1];
    int hard = (z1 > z0) ? 1 : 0;   // jnp.argmax ties -> 0
    rsh[0] = hard ? 0.0f : 1.0f; rsh[1] = hard ? 1.0f : 0.0f;
    rout[b * 2 + 0] = rsh[0]; rout[b * 2 + 1] = rsh[1];
  }
  __syncthreads();
  const float r0 = rsh[0], r1 = rsh[1];

  {
    const float* glb = gl + (long long)b * 4096;
    const int n = tid * 4;
    float4 gi4 = *(const float4*)(glb + n);
    float4 gf4 = *(const float4*)(glb + 1024 + n);
    float4 gg4 = *(const float4*)(glb + 2048 + n);
    float4 go4 = *(const float4*)(glb + 3072 + n);
    float4 co4 = *(const float4*)(cl_o + (long long)b * 1024 + n);
    float4 ho4 = *(const float4*)(hl_o + (long long)b * 1024 + n);
    float gi[4] = {gi4.x, gi4.y, gi4.z, gi4.w};
    float gf[4] = {gf4.x, gf4.y, gf4.z, gf4.w};
    float gg[4] = {gg4.x, gg4.y, gg4.z, gg4.w};
    float go[4] = {go4.x, go4.y, go4.z, go4.w};
    float co[4] = {co4.x, co4.y, co4.z, co4.w};
    float ho[4] = {ho4.x, ho4.y, ho4.z, ho4.w};
    float hv[4], cv[4];
    f16x4 ih, il;
#pragma unroll
    for (int e = 0; e < 4; ++e) {
      float cln = sigf(gf[e]) * co[e] + sigf(gi[e]) * tanhf(gg[e]);
      float hln = sigf(go[e]) * tanhf(cln);
      float ph = (n + e < 512) ? shs[n + e] : ho[e];
      float pc = (n + e < 512) ? scs[n + e] : co[e];
      hv[e] = r0 * hln + r1 * ph;
      cv[e] = r0 * cln + r1 * pc;
      ih[e] = (f16)hv[e]; il[e] = (f16)(hv[e] - (float)ih[e]);
    }
    float4 hw = {hv[0], hv[1], hv[2], hv[3]};
    float4 cw = {cv[0], cv[1], cv[2], cv[3]};
    *(float4*)(hl_n + (long long)b * 1024 + n) = hw;
    *(float4*)(cl_n + (long long)b * 1024 + n) = cw;
    // hl image (KT=32): n..n+3 share kt,fq; e base = n&7 (0 or 4)
    const int kt = n >> 5, fqn = (n >> 3) & 3, en = n & 7;
    const long long o = (((long long)pb * 32 + kt) * 8 + jb) * 512
                      + (fqn * 16 + frb) * 8 + en;
    *(f16x4*)(hlIh + o) = ih;
    *(f16x4*)(hlIl + o) = il;
  }
}

// logits = h_l @ W_c^T + b_c
__global__ __launch_bounds__(256) void logits_k(const float* __restrict__ hl,
                                                const float* __restrict__ Wc,
                                                const float* __restrict__ bc,
                                                float* __restrict__ out)
{
  __shared__ float hsd[1024];
  const int b = blockIdx.x, tid = threadIdx.x;
  *(float4*)(hsd + tid * 4) = *(const float4*)(hl + (long long)b * 1024 + tid * 4);
  __syncthreads();
  if (tid < 239) {
    const float* w = Wc + (long long)tid * 1024;
    float s = 0.0f;
    for (int k = 0; k < 1024; k += 4) {
      float4 wv = *(const float4*)(w + k);
      s += hsd[k] * wv.x + hsd[k + 1] * wv.y + hsd[k + 2] * wv.z + hsd[k + 3] * wv.w;
    }
    out[(long long)b * 239 + tid] = s + bc[tid];
  }
}

// ===========================================================================
// all-f32 fallback (tiny workspace) — Round-1 proven path
#define BKK 32
template <int BM, int BN, int TM, int TN, int EPI>
__global__ __launch_bounds__(256) void gemm_nt(
    int M, int N,
    const float* __restrict__ A0, long long as0, const float* __restrict__ B0, long long bs0, int K0,
    const float* __restrict__ A1, long long as1, const float* __restrict__ B1, long long bs1, int K1,
    const float* __restrict__ A2, long long as2, const float* __restrict__ B2, long long bs2, int K2,
    float* __restrict__ C, long long ldc,
    const float* __restrict__ e0, const float* __restrict__ e1, const float* __restrict__ e2)
{
  __shared__ float As[BKK][BM + 4];
  __shared__ float Bs[BKK][BN + 4];
  const int tid = threadIdx.x;
  const int m0 = blockIdx.x * BM;
  const int n0 = blockIdx.y * BN;
  constexpr int C4 = BKK / 4;
  constexpr int RPP = 256 / C4;
  constexpr int APASS = BM / RPP;
  constexpr int BPASS = BN / RPP;
  const int lr = tid / C4;
  const int lc = tid % C4;
  float4 pa[APASS], pb[BPASS];
  const int nt = (K0 + K1 + K2) / BKK;
  auto load = [&](int kt) {
    const int kg = kt * BKK;
    const float* ap; long long as_; const float* bp; long long bs_;
    if (kg < K0)           { ap = A0 + kg;          as_ = as0; bp = B0 + kg;          bs_ = bs0; }
    else if (kg < K0 + K1) { int kl = kg - K0;      ap = A1 + kl; as_ = as1; bp = B1 + kl; bs_ = bs1; }
    else                   { int kl = kg - K0 - K1; ap = A2 + kl; as_ = as2; bp = B2 + kl; bs_ = bs2; }
#pragma unroll
    for (int p = 0; p < APASS; p++) {
      int r = lr + p * RPP;
      pa[p] = *(const float4*)(ap + (long long)(m0 + r) * as_ + lc * 4);
    }
#pragma unroll
    for (int p = 0; p < BPASS; p++) {
      int r = lr + p * RPP;
      pb[p] = *(const float4*)(bp + (long long)(n0 + r) * bs_ + lc * 4);
    }
  };
  const int tx = tid % (BN / TN);
  const int ty = tid / (BN / TN);
  float acc[TM][TN];
#pragma unroll
  for (int i = 0; i < TM; i++)
#pragma unroll
    for (int j = 0; j < TN; j++) acc[i][j] = 0.0f;
  load(0);
  for (int kt = 0; kt < nt; ++kt) {
    __syncthreads();
#pragma unroll
    for (int p = 0; p < APASS; p++) {
      int r = lr + p * RPP;
      As[lc * 4 + 0][r] = pa[p].x; As[lc * 4 + 1][r] = pa[p].y;
      As[lc * 4 + 2][r] = pa[p].z; As[lc * 4 + 3][r] = pa[p].w;
    }
#pragma unroll
    for (int p = 0; p < BPASS; p++) {
      int r = lr + p * RPP;
      Bs[lc * 4 + 0][r] = pb[p].x; Bs[lc * 4 + 1][r] = pb[p].y;
      Bs[lc * 4 + 2][r] = pb[p].z; Bs[lc * 4 + 3][r] = pb[p].w;
    }
    __syncthreads();
    if (kt + 1 < nt) load(kt + 1);
#pragma unroll
    for (int k = 0; k < BKK; k++) {
      float a[TM], bfr[TN];
#pragma unroll
      for (int i = 0; i < TM; i++) a[i] = As[k][ty * TM + i];
#pragma unroll
      for (int j = 0; j < TN; j++) bfr[j] = Bs[k][tx * TN + j];
#pragma unroll
      for (int i = 0; i < TM; i++)
#pragma unroll
        for (int j = 0; j < TN; j++) acc[i][j] += a[i] * bfr[j];
    }
  }
#pragma unroll
  for (int i = 0; i < TM; i++) {
    const int m = m0 + ty * TM + i;
    const int n = n0 + tx * TN;
    float v[TN];
#pragma unroll
    for (int j = 0; j < TN; j++) {
      float a = acc[i][j];
      if (EPI == 0) {
        float s = e1[n + j] * 0.999995f;
        a = (a + e0[n + j]) * s + e2[n + j];
        a = fmaxf(a, 0.0f);
      } else {
        a = a + e0[n + j] + e1[n + j];
      }
      v[j] = a;
    }
    float4 o; o.x = v[0]; o.y = v[1]; o.z = v[2]; o.w = v[3];
    *(float4*)(C + (long long)m * ldc + n) = o;
  }
}

__global__ __launch_bounds__(256) void zs32_k(const float* __restrict__ sf,
                                              const float* __restrict__ Wg,
                                              float* __restrict__ zs)
{
  const int wave = threadIdx.x >> 6, lane = threadIdx.x & 63;
  const int row = blockIdx.x * 4 + wave;
  const float* s = sf + (long long)row * 512 + lane * 8;
  const float* w0 = Wg + lane * 8;
  const float* w1 = Wg + 2560 + lane * 8;
  float4 sa = *(const float4*)s, sb = *(const float4*)(s + 4);
  float4 a0 = *(const float4*)w0, b0 = *(const float4*)(w0 + 4);
  float4 a1 = *(const float4*)w1, b1 = *(const float4*)(w1 + 4);
  float z0 = sa.x * a0.x + sa.y * a0.y + sa.z * a0.z + sa.w * a0.w
           + sb.x * b0.x + sb.y * b0.y + sb.z * b0.z + sb.w * b0.w;
  float z1 = sa.x * a1.x + sa.y * a1.y + sa.z * a1.z + sa.w * a1.w
           + sb.x * b1.x + sb.y * b1.y + sb.z * b1.z + sb.w * b1.w;
#pragma unroll
  for (int off = 32; off > 0; off >>= 1) {
    z0 += __shfl_down(z0, off);
    z1 += __shfl_down(z1, off);
  }
  if (lane == 0) { zs[row * 2] = z0; zs[row * 2 + 1] = z1; }
}

// fallback f32 step update (no image writes)
__global__ __launch_bounds__(256) void step_upd32(
    const float* __restrict__ gl, const float* __restrict__ gs,
    const float* __restrict__ hl_o, const float* __restrict__ cl_o,
    const float* __restrict__ cs_o,
    float* __restrict__ hl_n, float* __restrict__ cl_n,
    float* __restrict__ hs_n, float* __restrict__ cs_n,
    const float* __restrict__ zs, const float* __restrict__ Wg,
    const float* __restrict__ bg, float* __restrict__ rout, int t)
{
  const int b = blockIdx.x, tid = threadIdx.x;
  __shared__ float red0[256], red1[256];
  __shared__ float shs[512], scs[512];
  __shared__ float rsh[2];
  float4 h4 = *(const float4*)(hl_o + (long long)b * 1024 + tid * 4);
  float4 c4 = *(const float4*)(cl_o + (long long)b * 1024 + tid * 4);
  float4 w0h = *(const float4*)(Wg + 512 + tid * 4);
  float4 w0c = *(const float4*)(Wg + 1536 + tid * 4);
  float4 w1h = *(const float4*)(Wg + 2560 + 512 + tid * 4);
  float4 w1c = *(const float4*)(Wg + 2560 + 1536 + tid * 4);
  red0[tid] = h4.x * w0h.x + h4.y * w0h.y + h4.z * w0h.z + h4.w * w0h.w
            + c4.x * w0c.x + c4.y * w0c.y + c4.z * w0c.z + c4.w * w0c.w;
  red1[tid] = h4.x * w1h.x + h4.y * w1h.y + h4.z * w1h.z + h4.w * w1h.w
            + c4.x * w1c.x + c4.y * w1c.y + c4.z * w1c.z + c4.w * w1c.w;
  {
    const float* gb = gs + (long long)b * 2048;
#pragma unroll
    for (int e = 0; e < 2; ++e) {
      const int n = tid * 2 + e;
      float gi = gb[n], gf = gb[512 + n], gg = gb[1024 + n], go = gb[1536 + n];
      float c2 = sigf(gf) * cs_o[b * 512 + n] + sigf(gi) * tanhf(gg);
      float h2 = sigf(go) * tanhf(c2);
      shs[n] = h2; scs[n] = c2;
      hs_n[b * 512 + n] = h2; cs_n[b * 512 + n] = c2;
    }
  }
  __syncthreads();
  for (int s = 128; s > 0; s >>= 1) {
    if (tid < s) { red0[tid] += red0[tid + s]; red1[tid] += red1[tid + s]; }
    __syncthreads();
  }
  if (tid == 0) {
    float z0 = red0[0] + zs[(b * 64 + t) * 2 + 0] + bg[0];
    float z1 = red1[0] + zs[(b * 64 + t) * 2 + 1] + bg[1];
    int hard = (z1 > z0) ? 1 : 0;
    rsh[0] = hard ? 0.0f : 1.0f; rsh[1] = hard ? 1.0f : 0.0f;
    rout[b * 2 + 0] = rsh[0]; rout[b * 2 + 1] = rsh[1];
  }
  __syncthreads();
  const float r0 = rsh[0], r1 = rsh[1];
  {
    const float* glb = gl + (long long)b * 4096;
    const int n = tid * 4;
    float4 gi4 = *(const float4*)(glb + n);
    float4 gf4 = *(const float4*)(glb + 1024 + n);
    float4 gg4 = *(const float4*)(glb + 2048 + n);
    float4 go4 = *(const float4*)(glb + 3072 + n);
    float4 co4 = *(const float4*)(cl_o + (long long)b * 1024 + n);
    float4 ho4 = *(const float4*)(hl_o + (long long)b * 1024 + n);
    float gi[4] = {gi4.x, gi4.y, gi4.z, gi4.w};
    float gf[4] = {gf4.x, gf4.y, gf4.z, gf4.w};
    float gg[4] = {gg4.x, gg4.y, gg4.z, gg4.w};
    float go[4] = {go4.x, go4.y, go4.z, go4.w};
    float co[4] = {co4.x, co4.y, co4.z, co4.w};
    float ho[4] = {ho4.x, ho4.y, ho4.z, ho4.w};
    float hv[4], cv[4];
#pragma unroll
    for (int e = 0; e < 4; ++e) {
      float cln = sigf(gf[e]) * co[e] + sigf(gi[e]) * tanhf(gg[e]);
      float hln = sigf(go[e]) * tanhf(cln);
      float ph = (n + e < 512) ? shs[n + e] : ho[e];
      float pc = (n + e < 512) ? scs[n + e] : co[e];
      hv[e] = r0 * hln + r1 * ph;
      cv[e] = r0 * cln + r1 * pc;
    }
    float4 hw = {hv[0], hv[1], hv[2], hv[3]};
    float4 cw = {cv[0], cv[1], cv[2], cv[3]};
    *(float4*)(hl_n + (long long)b * 1024 + n) = hw;
    *(float4*)(cl_n + (long long)b * 1024 + n) = cw;
  }
}

// ===========================================================================
extern "C" void kernel_launch(void* const* d_in, const int* in_sizes, int n_in,
                              void* d_out, int out_size, void* d_ws, size_t ws_size,
                              hipStream_t stream)
{
  const float* x     = (const float*)d_in[0];
  const float* xs    = (const float*)d_in[1];
  const float* W_p   = (const float*)d_in[2];
  const float* b_p   = (const float*)d_in[3];
  const float* g_p   = (const float*)d_in[4];
  const float* be_p  = (const float*)d_in[5];
  const float* W_s   = (const float*)d_in[6];
  const float* b_s   = (const float*)d_in[7];
  const float* g_s   = (const float*)d_in[8];
  const float* be_s  = (const float*)d_in[9];
  const float* Wih_l = (const float*)d_in[10];
  const float* Whh_l = (const float*)d_in[11];
  const float* bih_l = (const float*)d_in[12];
  const float* bhh_l = (const float*)d_in[13];
  const float* Wih_s = (const float*)d_in[14];
  const float* Whh_s = (const float*)d_in[15];
  const float* bih_s = (const float*)d_in[16];
  const float* bhh_s = (const float*)d_in[17];
  const float* W_g   = (const float*)d_in[18];
  const float* b_g   = (const float*)d_in[19];
  const float* W_c   = (const float*)d_in[20];
  const float* b_c   = (const float*)d_in[21];
  float* out = (float*)d_out;
  float* r_out = out + 61184;            // [64][256][2]

  const int BT = 16384;
  const size_t FIXEDB = 100794368ULL;
  const size_t CHUNKB = 12320768ULL;
  int Tp = 0;
  for (int T = 64; T >= 1; T >>= 1)
    if (FIXEDB + CHUNKB * (size_t)T + 65536 <= ws_size) { Tp = T; break; }

  if (Tp > 0) {
    char* base = (char*)d_ws;
    size_t off = 0;
    auto alloc = [&](size_t n) { void* p = base + off; off += (n + 255) & ~255ULL; return p; };
    f16* WpI[2]  = {(f16*)alloc(8388608),  (f16*)alloc(8388608)};
    f16* WsI[2]  = {(f16*)alloc(1310720),  (f16*)alloc(1310720)};
    f16* WilI[2] = {(f16*)alloc(20971520), (f16*)alloc(20971520)};
    f16* WisI[2] = {(f16*)alloc(2097152),  (f16*)alloc(2097152)};
    f16* WhlI[2] = {(f16*)alloc(8388608),  (f16*)alloc(8388608)};
    f16* WhsI[2] = {(f16*)alloc(2097152),  (f16*)alloc(2097152)};
    f16* hlI[2] = {(f16*)alloc(524288), (f16*)alloc(524288)};
    f16* hsI[2] = {(f16*)alloc(262144), (f16*)alloc(262144)};
    float* zs  = (float*)alloc(131072);
    float* hl[2] = {(float*)alloc(1048576), (float*)alloc(1048576)};
    float* cl[2] = {(float*)alloc(1048576), (float*)alloc(1048576)};
    float* hsb[2] = {(float*)alloc(524288), (float*)alloc(524288)};
    float* csb[2] = {(float*)alloc(524288), (float*)alloc(524288)};
    float* gates_l = (float*)alloc(4194304);
    float* gates_s = (float*)alloc(2097152);
    f16* xI[2]  = {(f16*)alloc(1048576ULL * Tp), (f16*)alloc(1048576ULL * Tp)};
    f16* xsI[2] = {(f16*)alloc(655360ULL * Tp),  (f16*)alloc(655360ULL * Tp)};
    f16* feI[2] = {(f16*)alloc(1048576ULL * Tp), (f16*)alloc(1048576ULL * Tp)};
    f16* sfI[2] = {(f16*)alloc(262144ULL * Tp),  (f16*)alloc(262144ULL * Tp)};
    float* GxlC = (float*)alloc(4194304ULL * Tp);
    float* GxsC = (float*)alloc(2097152ULL * Tp);

    // one-time weight packs
    pack_img<<<2048, 256, 0, stream>>>(W_p,   2048, 64, 0, 0, WpI[0],  WpI[1],  524288);
    pack_img<<<320,  256, 0, stream>>>(W_s,   1280, 40, 0, 0, WsI[0],  WsI[1],  81920);
    pack_img<<<5120, 256, 0, stream>>>(Wih_l, 2560, 80, 0, 0, WilI[0], WilI[1], 1310720);
    pack_img<<<512,  256, 0, stream>>>(Wih_s, 512,  16, 0, 0, WisI[0], WisI[1], 131072);
    pack_img<<<2048, 256, 0, stream>>>(Whh_l, 1024, 32, 0, 0, WhlI[0], WhlI[1], 524288);
    pack_img<<<512,  256, 0, stream>>>(Whh_s, 512,  16, 0, 0, WhsI[0], WhsI[1], 131072);

    hipMemsetAsync(hl[0], 0, 1048576, stream);
    hipMemsetAsync(cl[0], 0, 1048576, stream);
    hipMemsetAsync(hsb[0], 0, 524288, stream);
    hipMemsetAsync(csb[0], 0, 524288, stream);
    hipMemsetAsync(hlI[0], 0, 524288, stream);
    hipMemsetAsync(hlI[1], 0, 524288, stream);
    hipMemsetAsync(hsI[0], 0, 262144, stream);
    hipMemsetAsync(hsI[1], 0, 262144, stream);

    const int rows = 256 * Tp;             // chunk rows (time-major)
    for (int t0 = 0; t0 < 64; t0 += Tp) {
      pack_img<<<rows * 2048 / 8 / 256, 256, 0, stream>>>(
          x, 2048, 64, t0, 1, xI[0], xI[1], rows * 256);
      pack_img<<<rows * 1280 / 8 / 256, 256, 0, stream>>>(
          xs, 1280, 40, t0, 1, xsI[0], xsI[1], rows * 160);
      // sfeats chunk -> sf image (256^2 tiles)
      gmm256<0><<<dim3(2, rows / 256), 512, 0, stream>>>(
          xsI[0], xsI[1], 40, nullptr, nullptr, 0,
          WsI[0], WsI[1], 40,
          nullptr, 0, sfI[0], sfI[1], 16, b_s, g_s, be_s);
      zs_img_k<<<rows / 4, 256, 0, stream>>>(sfI[0], sfI[1], W_g, zs, t0);
      // feats chunk -> fe image
      gmm256<0><<<dim3(8, rows / 256), 512, 0, stream>>>(
          xI[0], xI[1], 64, nullptr, nullptr, 0,
          WpI[0], WpI[1], 64,
          nullptr, 0, feI[0], feI[1], 64, b_p, g_p, be_p);
      // Gx_l = [fe|sf] @ Wih_l^T + bih_l + bhh_l
      gmm256<1><<<dim3(16, rows / 256), 512, 0, stream>>>(
          feI[0], feI[1], 64, sfI[0], sfI[1], 16,
          WilI[0], WilI[1], 80,
          GxlC, 4096, nullptr, nullptr, 0, bih_l, bhh_l, nullptr);
      // Gx_s = sf @ Wih_s^T + bih_s + bhh_s
      gmm256<1><<<dim3(8, rows / 256), 512, 0, stream>>>(
          sfI[0], sfI[1], 16, nullptr, nullptr, 0,
          WisI[0], WisI[1], 16,
          GxsC, 2048, nullptr, nullptr, 0, bih_s, bhh_s, nullptr);

      for (int tt = 0; tt < Tp; ++tt) {
        const int t = t0 + tt;
        const int o = t & 1, nw = o ^ 1;
        stepg_k<<<dim3(2, 48), 256, 0, stream>>>(
            hlI[0], hlI[1], hsI[0], hsI[1],
            WhlI[0], WhlI[1], WhsI[0], WhsI[1],
            GxlC + (long long)tt * 256 * 4096, GxsC + (long long)tt * 256 * 2048,
            gates_l, gates_s);
        step_upd<<<256, 256, 0, stream>>>(
            gates_l, gates_s, hl[o], cl[o], csb[o],
            hl[nw], cl[nw], hsb[nw], csb[nw],
            hlI[0], hlI[1], hsI[0], hsI[1],
            zs, W_g, b_g, r_out + (long long)t * 512, t);
      }
    }
    logits_k<<<256, 256, 0, stream>>>(hl[0], W_c, b_c, out);
    return;
  }

  // ---------------- all-f32 fallback (tiny workspace) ----------------
  float* ws = (float*)d_ws;
  size_t offf = 0;
  auto allocf = [&](size_t n) { float* p = ws + offf; offf += n; return p; };
  float* feats   = allocf((size_t)BT * 2048);
  float* sfeats  = allocf((size_t)BT * 512);
  float* zs      = allocf((size_t)BT * 2);
  float* gates_l = allocf((size_t)256 * 4096);
  float* gates_s = allocf((size_t)256 * 2048);
  float* hl[2] = { allocf(256 * 1024), allocf(256 * 1024) };
  float* cl[2] = { allocf(256 * 1024), allocf(256 * 1024) };
  float* hsb[2] = { allocf(256 * 512),  allocf(256 * 512) };
  float* csb[2] = { allocf(256 * 512),  allocf(256 * 512) };

  hipMemsetAsync(hl[0], 0, 256 * 1024 * sizeof(float), stream);
  hipMemsetAsync(cl[0], 0, 256 * 1024 * sizeof(float), stream);
  hipMemsetAsync(hsb[0], 0, 256 * 512 * sizeof(float), stream);
  hipMemsetAsync(csb[0], 0, 256 * 512 * sizeof(float), stream);

  gemm_nt<128, 64, 8, 4, 0><<<dim3(BT / 128, 2048 / 64), 256, 0, stream>>>(
      BT, 2048, x, 2048, W_p, 2048, 2048,
      nullptr, 0, nullptr, 0, 0, nullptr, 0, nullptr, 0, 0,
      feats, 2048, b_p, g_p, be_p);
  gemm_nt<128, 64, 8, 4, 0><<<dim3(BT / 128, 512 / 64), 256, 0, stream>>>(
      BT, 512, xs, 1280, W_s, 1280, 1280,
      nullptr, 0, nullptr, 0, 0, nullptr, 0, nullptr, 0, 0,
      sfeats, 512, b_s, g_s, be_s);
  zs32_k<<<BT / 4, 256, 0, stream>>>(sfeats, W_g, zs);

  for (int t = 0; t < 64; ++t) {
    const int o = t & 1, nw = o ^ 1;
    gemm_nt<64, 64, 4, 4, 1><<<dim3(4, 2048 / 64), 256, 0, stream>>>(
        256, 2048, sfeats + (long long)t * 512, 64LL * 512, Wih_s, 512, 512,
        hsb[o], 512, Whh_s, 512, 512, nullptr, 0, nullptr, 0, 0,
        gates_s, 2048, bih_s, bhh_s, nullptr);
    gemm_nt<64, 64, 4, 4, 1><<<dim3(4, 4096 / 64), 256, 0, stream>>>(
        256, 4096, feats + (long long)t * 2048, 64LL * 2048, Wih_l, 2560, 2048,
        sfeats + (long long)t * 512, 64LL * 512, Wih_l + 2048, 2560, 512,
        hl[o], 1024, Whh_l, 1024, 1024,
        gates_l, 4096, bih_l, bhh_l, nullptr);
    step_upd32<<<256, 256, 0, stream>>>(
        gates_l, gates_s, hl[o], cl[o], csb[o],
        hl[nw], cl[nw], hsb[nw], csb[nw],
        zs, W_g, b_g, r_out + (long long)t * 512, t);
  }
  logits_k<<<256, 256, 0, stream>>>(hl[0], W_c, b_c, out);
}